// Round 1
// baseline (361.003 us; speedup 1.0000x reference)
//
#include <hip/hip_runtime.h>
#include <hip/hip_bf16.h>

// Problem constants
#define HWSZ   262144   // 512*512
#define IMG    512
#define NBATCH 4
#define NBANDS 8

typedef _Float16 half_t;
typedef _Float16 half2v __attribute__((ext_vector_type(2)));
typedef _Float16 half4v __attribute__((ext_vector_type(4)));
typedef _Float16 half8v __attribute__((ext_vector_type(8)));

// ---------------------------------------------------------------------------
// Block-level reduction: wave shuffle + LDS + one double atomic per block.
__device__ __forceinline__ void blockReduceAtomicAdd(double v, double* target,
                                                     double* red) {
    for (int off = 32; off > 0; off >>= 1) v += __shfl_down(v, off, 64);
    const int wave = threadIdx.x >> 6, lane = threadIdx.x & 63;
    if (lane == 0) red[wave] = v;
    __syncthreads();
    if (threadIdx.x == 0) atomicAdd(target, red[0] + red[1] + red[2] + red[3]);
}

// ---------------------------------------------------------------------------
// Pan smoothing (edge-pad 41x41 Gaussian, rank-1 factored), horizontal pass.
__global__ __launch_bounds__(256) void k_pan_h(const float* __restrict__ inp,
                                               const float* __restrict__ mtf,
                                               float* __restrict__ tmpH) {
    __shared__ float seg[296];
    __shared__ float vrow[41];
    const int tid = threadIdx.x;
    const int b = blockIdx.z, r = blockIdx.y, c0 = blockIdx.x * 256;
    if (tid < 41) vrow[tid] = mtf[20 * 41 + tid] / sqrtf(mtf[20 * 41 + 20]);
    const float* pan = inp + ((long)b * 9 + 8) * HWSZ + (long)r * IMG;
    for (int e = tid; e < 296; e += 256) {
        int c = c0 - 20 + e;
        c = min(max(c, 0), IMG - 1);
        seg[e] = pan[c];
    }
    __syncthreads();
    float s = 0.f;
#pragma unroll
    for (int j = 0; j < 41; ++j) s += vrow[j] * seg[tid + j];
    tmpH[(long)b * HWSZ + (long)r * IMG + c0 + tid] = s;
}

__global__ __launch_bounds__(256) void k_pan_v(const float* __restrict__ tmpH,
                                               const float* __restrict__ mtf,
                                               float* __restrict__ panf) {
    __shared__ float ucol[41];
    const int tid = threadIdx.x;
    const int b = blockIdx.z, r = blockIdx.y, c = blockIdx.x * 256 + tid;
    if (tid < 41) ucol[tid] = mtf[tid * 41 + 20] / sqrtf(mtf[20 * 41 + 20]);
    __syncthreads();
    const float* base = tmpH + (long)b * HWSZ;
    float s = 0.f;
#pragma unroll
    for (int i = 0; i < 41; ++i) {
        int rr = min(max(r - 20 + i, 0), IMG - 1);
        s += ucol[i] * base[(long)rr * IMG + c];
    }
    panf[(long)b * HWSZ + (long)r * IMG + c] = s;
}

// ---------------------------------------------------------------------------
// Small-field (4-image) helpers, LDS tile based (cheap at this size).
template <int W>
__global__ __launch_bounds__(256) void k_da(const float* __restrict__ in,
                                            long inBatchStride,
                                            float* __restrict__ out) {
    constexpr int TS = 32, WIN = 2 * W, NN = 4 * W * W, RE = TS + WIN - 1;
    constexpr int SR = RE;
    constexpr int ST = 33;
    __shared__ float RAW[RE * SR];
    __shared__ float T[RE * ST];
    const int tid = threadIdx.x;
    const int tr0 = blockIdx.y * TS, tc0 = blockIdx.x * TS;
    const float* src = in + (long)blockIdx.z * inBatchStride;
    for (int e = tid; e < RE * RE; e += 256) {
        int r = e / RE, c = e % RE;
        int gr = tr0 - (W - 1) + r, gc = tc0 - (W - 1) + c;
        float v = 0.f;
        if (gr >= 0 && gr < IMG && gc >= 0 && gc < IMG) v = src[(long)gr * IMG + gc];
        RAW[r * SR + c] = v;
    }
    __syncthreads();
    for (int e = tid; e < RE * TS; e += 256) {
        int r = e >> 5, j = e & 31;
        float s = 0.f;
#pragma unroll
        for (int k = 0; k < WIN; ++k) s += RAW[r * SR + j + k];
        T[r * ST + j] = s;
    }
    __syncthreads();
    float* dst = out + (long)blockIdx.z * HWSZ;
    for (int e = tid; e < TS * TS; e += 256) {
        int pr = e >> 5, pc = e & 31;
        float s = 0.f;
#pragma unroll
        for (int k = 0; k < WIN; ++k) s += T[(pr + k) * ST + pc];
        float da = RAW[(pr + W - 1) * SR + (pc + W - 1)] - s * (1.0f / NN);
        dst[(long)(tr0 + pr) * IMG + tc0 + pc] = da;
    }
}

template <int W>
__global__ __launch_bounds__(256) void k_sq(const float* __restrict__ in,
                                            float* __restrict__ out) {
    constexpr int TS = 32, WIN = 2 * W, RE = TS + WIN - 1;
    constexpr int SR = RE, ST = 33;
    __shared__ float RAW[RE * SR];
    __shared__ float T[RE * ST];
    const int tid = threadIdx.x;
    const int tr0 = blockIdx.y * TS, tc0 = blockIdx.x * TS;
    const float* src = in + (long)blockIdx.z * HWSZ;
    for (int e = tid; e < RE * RE; e += 256) {
        int r = e / RE, c = e % RE;
        int gr = tr0 - (W - 1) + r, gc = tc0 - (W - 1) + c;
        float v = 0.f;
        if (gr >= 0 && gr < IMG && gc >= 0 && gc < IMG) v = src[(long)gr * IMG + gc];
        RAW[r * SR + c] = v;
    }
    __syncthreads();
    for (int e = tid; e < RE * TS; e += 256) {
        int r = e >> 5, j = e & 31;
        float s = 0.f;
#pragma unroll
        for (int k = 0; k < WIN; ++k) {
            float v = RAW[r * SR + j + k];
            s += v * v;
        }
        T[r * ST + j] = s;
    }
    __syncthreads();
    float* dst = out + (long)blockIdx.z * HWSZ;
    for (int e = tid; e < TS * TS; e += 256) {
        int pr = e >> 5, pc = e & 31;
        float s = 0.f;
#pragma unroll
        for (int k = 0; k < WIN; ++k) s += T[(pr + k) * ST + pc];
        dst[(long)(tr0 + pr) * IMG + tc0 + pc] = s;
    }
}

// ---------------------------------------------------------------------------
// Full-size (32-image) separable box passes, zero LDS, register sliding.
// Intermediates fp16 (t, da). Error budget: thr/X err ~2e-3,
// loss err ~1e-3 << 1.3e-2 threshold (measured absmax 0.0 at fp16).

template <int W> struct WinDims {
    static constexpr int A  = (W + 3) & ~3;
    static constexpr int NU = A + W + 8;              // elements actually used
    static constexpr int NF = (NU + 3) / 4;           // 4-elem chunks loaded
    static constexpr int NV = NF * 4;                 // padded array size
};

template <int W>
__device__ __forceinline__ void loadRowWin(const float* __restrict__ row, int c0,
                                           float* v) {
    constexpr int A = WinDims<W>::A;
    constexpr int NF = WinDims<W>::NF;
#pragma unroll
    for (int f = 0; f < NF; ++f) {
        const int cb = c0 - A + 4 * f;
        if (cb >= 0 && cb + 3 < IMG) {
            const float4 t = *(const float4*)(row + cb);
            v[4 * f + 0] = t.x; v[4 * f + 1] = t.y;
            v[4 * f + 2] = t.z; v[4 * f + 3] = t.w;
        } else {
#pragma unroll
            for (int u = 0; u < 4; ++u) {
                const int c = cb + u;
                v[4 * f + u] = (c >= 0 && c < IMG) ? row[c] : 0.f;
            }
        }
    }
}

// H box of a raw fp32 input field -> t (half, z*HWSZ layout). grid 4096 x 256.
template <int W>
__global__ __launch_bounds__(256) void kHbox(const float* __restrict__ in,
                                             long sB, long sC,
                                             half_t* __restrict__ out) {
    constexpr int A = WinDims<W>::A;
    const int g = blockIdx.x * 256 + threadIdx.x;
    const int c0 = (g & 63) << 3, r = (g >> 6) & 511, z = g >> 15;
    const float* row = in + (long)(z >> 3) * sB + (long)(z & 7) * sC + (long)r * IMG;
    float v[WinDims<W>::NV];
    loadRowWin<W>(row, c0, v);
    float o[8];
    float s = 0.f;
#pragma unroll
    for (int i = A - W + 1; i <= A + W; ++i) s += v[i];
    o[0] = s;
#pragma unroll
    for (int j = 1; j < 8; ++j) {
        s += v[A + W + j] - v[A - W + j];
        o[j] = s;
    }
    half8v h;
#pragma unroll
    for (int j = 0; j < 8; ++j) h[j] = (half_t)o[j];
    *(half8v*)(out + (long)z * HWSZ + (long)r * IMG + c0) = h;   // 16B aligned
}

// V box of t (half) + epilogue da = orig - box/n (half out).
// 2 columns/thread via half2/float2 loads. grid 1024 x 256.
template <int W>
__global__ __launch_bounds__(256) void kVda(const half_t* __restrict__ t,
                                            const float* __restrict__ orig,
                                            long sB, long sC,
                                            half_t* __restrict__ out) {
    constexpr int NR = 2 * W + 15, NN = 4 * W * W;
    const int g = blockIdx.x * 256 + threadIdx.x;
    const int cp = (g & 255) * 2;          // even column pair base
    const int rc = (g >> 8) & 31, z = g >> 13;
    const int r0 = rc * 16;
    const half_t* tz = t + (long)z * HWSZ + cp;
    float vx[NR], vy[NR];
#pragma unroll
    for (int i = 0; i < NR; ++i) {
        const int rr = r0 - W + 1 + i;
        if (rr >= 0 && rr < IMG) {
            const half2v h = *(const half2v*)(tz + (long)rr * IMG);
            vx[i] = (float)h[0]; vy[i] = (float)h[1];
        } else { vx[i] = 0.f; vy[i] = 0.f; }
    }
    const float* oz = orig + (long)(z >> 3) * sB + (long)(z & 7) * sC + cp;
    half_t* dst = out + (long)z * HWSZ + cp;
    float sx = 0.f, sy = 0.f;
#pragma unroll
    for (int i = 0; i < 2 * W; ++i) { sx += vx[i]; sy += vy[i]; }
#pragma unroll
    for (int j = 0; j < 16; ++j) {
        const float2 o = *(const float2*)(oz + (long)(r0 + j) * IMG);
        half2v h;
        h[0] = (half_t)(o.x - sx * (1.0f / NN));
        h[1] = (half_t)(o.y - sy * (1.0f / NN));
        *(half2v*)(dst + (long)(r0 + j) * IMG) = h;
        if (j < 15) {
            sx += vx[2 * W + j] - vx[j];
            sy += vy[2 * W + j] - vy[j];
        }
    }
}

// ---------------------------------------------------------------------------
// Fused product + H-box + V-box + thr/X/Y kernel (replaces kHprod<8>,
// kHprod<2>, kVfinBoth). One 32x32 output tile per block, both xcorr widths
// computed back-to-back reusing the same LDS. Products staged in fp32 LDS
// (MORE precise than the old fp16 hP/hQ intermediates). Eliminates 64 MB of
// intermediate writes + ~100 MB of latency-exposed column-strided reads.
// grid (16,16,32) x 256.
__global__ __launch_bounds__(256) void kXfused(
    const half_t* __restrict__ daMS,   // 32 imgs half: da of inp ms bands
    const float*  __restrict__ daPAN,  // 4 imgs fp32: da of smoothed pan
    const float*  __restrict__ saa,    // 4 imgs fp32: box(daPAN^2), w=8
    const half_t* __restrict__ daOUT,  // 32 imgs half: da of outputs
    const float*  __restrict__ dbPAN,  // 4 imgs fp32: db of label pan
    const float*  __restrict__ sbb,    // 4 imgs fp32: box(dbPAN^2), w=2
    double* __restrict__ acc) {
    constexpr int TS = 32;
    constexpr int RE8 = TS + 15, SR8 = RE8 + 1;    // 47, 48
    constexpr int RE2 = TS + 3,  SR2 = RE2 + 1;    // 35, 36
    constexpr int ST  = TS + 1;                    // 33
    __shared__ double red[4];
    __shared__ float P1[RE8 * SR8];                // products (fp32)
    __shared__ float P2[RE8 * SR8];
    __shared__ float T1[RE8 * ST];                 // H-box sums
    __shared__ float T2[RE8 * ST];

    const int tid = threadIdx.x;
    const int z = blockIdx.z, b = z >> 3;
    const int tr0 = blockIdx.y * TS, tc0 = blockIdx.x * TS;

    float thrv[4];
    {   // ---------------- w = 8 phase: thr ----------------
        constexpr int W = 8, RE = RE8, SR = SR8, WIN = 16;
        const half_t* A = daMS + (long)z * HWSZ;
        const float*  S = daPAN + (long)b * HWSZ;
        for (int e = tid; e < RE * RE; e += 256) {
            const int r = e / RE, c = e % RE;
            const int gr = tr0 - (W - 1) + r, gc = tc0 - (W - 1) + c;
            float a = 0.f, s = 0.f;
            if (gr >= 0 && gr < IMG && gc >= 0 && gc < IMG) {
                a = (float)A[(long)gr * IMG + gc];
                s = S[(long)gr * IMG + gc];
            }
            P1[r * SR + c] = a * s;                // da_pan * da_ms
            P2[r * SR + c] = a * a;                // da_ms^2
        }
        __syncthreads();
        for (int e = tid; e < RE * TS; e += 256) {
            const int r = e >> 5, j = e & 31;
            float s1 = 0.f, s2 = 0.f;
#pragma unroll
            for (int k = 0; k < WIN; ++k) {
                s1 += P1[r * SR + j + k];
                s2 += P2[r * SR + j + k];
            }
            T1[r * ST + j] = s1;
            T2[r * ST + j] = s2;
        }
        __syncthreads();
        const float* sz = saa + (long)b * HWSZ;
#pragma unroll
        for (int k = 0; k < 4; ++k) {
            const int e = tid + 256 * k;
            const int pr = e >> 5, pc = e & 31;
            float s1 = 0.f, s2 = 0.f;
#pragma unroll
            for (int kk = 0; kk < WIN; ++kk) {
                s1 += T1[(pr + kk) * ST + pc];
                s2 += T2[(pr + kk) * ST + pc];
            }
            const float sa = sz[(long)(tr0 + pr) * IMG + tc0 + pc];
            const float den = sqrtf(fmaxf(sa * s2, 0.f)) + 1e-20f;
            thrv[k] = 1.0f - s1 / den;
        }
        __syncthreads();   // protect LDS before w=2 overwrites it
    }
    double ysum = 0.0;
    {   // ---------------- w = 2 phase: X vs thr, Y ----------------
        constexpr int W = 2, RE = RE2, SR = SR2, WIN = 4;
        const half_t* A = daOUT + (long)z * HWSZ;
        const float*  S = dbPAN + (long)b * HWSZ;
        for (int e = tid; e < RE * RE; e += 256) {
            const int r = e / RE, c = e % RE;
            const int gr = tr0 - (W - 1) + r, gc = tc0 - (W - 1) + c;
            float a = 0.f, s = 0.f;
            if (gr >= 0 && gr < IMG && gc >= 0 && gc < IMG) {
                a = (float)A[(long)gr * IMG + gc];
                s = S[(long)gr * IMG + gc];
            }
            P1[r * SR + c] = a * s;                // da_out * db_pan
            P2[r * SR + c] = a * a;                // da_out^2
        }
        __syncthreads();
        for (int e = tid; e < RE * TS; e += 256) {
            const int r = e >> 5, j = e & 31;
            float s1 = 0.f, s2 = 0.f;
#pragma unroll
            for (int k = 0; k < WIN; ++k) {
                s1 += P1[r * SR + j + k];
                s2 += P2[r * SR + j + k];
            }
            T1[r * ST + j] = s1;
            T2[r * ST + j] = s2;
        }
        __syncthreads();
        const float* sz = sbb + (long)b * HWSZ;
#pragma unroll
        for (int k = 0; k < 4; ++k) {
            const int e = tid + 256 * k;
            const int pr = e >> 5, pc = e & 31;
            float s1 = 0.f, s2 = 0.f;
#pragma unroll
            for (int kk = 0; kk < WIN; ++kk) {
                s1 += T1[(pr + kk) * ST + pc];
                s2 += T2[(pr + kk) * ST + pc];
            }
            const float sb = sz[(long)(tr0 + pr) * IMG + tc0 + pc];
            const float den = sqrtf(fmaxf(s2 * sb, 0.f)) + 1e-20f;
            const float Xc = s1 / den;
            const float X = 1.0f - fmaxf(Xc, -1.0f);
            if (X > thrv[k]) ysum += (double)X;
        }
    }
    blockReduceAtomicAdd(ysum, acc + 2, red);
}

// ---------------------------------------------------------------------------
// L_spec: strided MTF conv of outputs (rank-1 factored), H then V+reduce.
__global__ __launch_bounds__(256) void k_spec_h(const float* __restrict__ outputs,
                                                const float* __restrict__ mtf,
                                                float* __restrict__ tmpS) {
    __shared__ float vrow[41];
    const int g = blockIdx.x * 256 + threadIdx.x;
    const int q = g & 31, r = (g >> 5) & 511, z = g >> 14;   // z uniform/block
    const int band = z & 7;
    if (threadIdx.x < 41)
        vrow[threadIdx.x] = mtf[band * 1681 + 20 * 41 + threadIdx.x] /
                            sqrtf(mtf[band * 1681 + 20 * 41 + 20]);
    __syncthreads();
    const float* row = outputs + (long)z * HWSZ + (long)r * IMG;
    float v[56];
#pragma unroll
    for (int f = 0; f < 14; ++f) {
        const int cb = 16 * q - 20 + 4 * f;
        if (cb >= 0 && cb + 3 < IMG) {
            const float4 t = *(const float4*)(row + cb);
            v[4 * f + 0] = t.x; v[4 * f + 1] = t.y;
            v[4 * f + 2] = t.z; v[4 * f + 3] = t.w;
        } else {
#pragma unroll
            for (int u = 0; u < 4; ++u) {
                const int cc = cb + u;
                v[4 * f + u] = (cc >= 0 && cc < IMG) ? row[cc] : 0.f;
            }
        }
    }
    float o[4] = {0.f, 0.f, 0.f, 0.f};
#pragma unroll
    for (int j = 0; j < 41; ++j) {
        const float w = vrow[j];
#pragma unroll
        for (int u = 0; u < 4; ++u) o[u] += w * v[2 + 4 * u + j];
    }
    float* dst = tmpS + ((long)z * IMG + r) * 128 + 4 * q;
    *(float4*)dst = make_float4(o[0], o[1], o[2], o[3]);
}

__global__ __launch_bounds__(256) void k_spec_v(const float* __restrict__ tmpS,
                                                const float* __restrict__ labels,
                                                const float* __restrict__ spec,
                                                const float* __restrict__ mtf,
                                                double* __restrict__ acc) {
    __shared__ double redT[4];
    __shared__ double redM[4];
    __shared__ float ucol[41];
    const int g = blockIdx.x * 256 + threadIdx.x;
    const int q = g & 31, rs = (g >> 5) & 127, z = g >> 12;   // z uniform/block
    const int b = z >> 3, band = z & 7;
    if (threadIdx.x < 41)
        ucol[threadIdx.x] = mtf[band * 1681 + threadIdx.x * 41 + 20] /
                            sqrtf(mtf[band * 1681 + 20 * 41 + 20]);
    __syncthreads();
    const float* base = tmpS + (long)z * IMG * 128 + 4 * q;
    const int rbase = 4 * rs - 18;
    float o[4] = {0.f, 0.f, 0.f, 0.f};
    if (rbase >= 0 && rbase + 40 < IMG) {
#pragma unroll
        for (int i = 0; i < 41; ++i) {
            const float4 v = *(const float4*)(base + (long)(rbase + i) * 128);
            const float w = ucol[i];
            o[0] += w * v.x; o[1] += w * v.y; o[2] += w * v.z; o[3] += w * v.w;
        }
    } else {
        for (int i = 0; i < 41; ++i) {
            const int r = rbase + i;
            if (r >= 0 && r < IMG) {
                const float4 v = *(const float4*)(base + (long)r * 128);
                const float w = ucol[i];
                o[0] += w * v.x; o[1] += w * v.y; o[2] += w * v.z; o[3] += w * v.w;
            }
        }
    }
    const int gr = 2 + 4 * rs;
    float tsum = 0.f, msum = 0.f;
#pragma unroll
    for (int u = 0; u < 4; ++u) {
        const int gc = 2 + 4 * (4 * q + u);
        const float m = spec[(long)band * HWSZ + (long)gr * IMG + gc];
        const float y = labels[((long)b * 9 + band) * HWSZ + (long)gr * IMG + gc];
        tsum += fabsf(o[u] * m - y * m);
        msum += m;
    }
    blockReduceAtomicAdd((double)tsum, acc + 0, redT);
    blockReduceAtomicAdd((double)msum, acc + 1, redM);
}

__global__ void k_final(const double* __restrict__ acc, float* __restrict__ out) {
    double lspec = acc[0] / acc[1];
    double lstruct = acc[2] / (double)(NBATCH * NBANDS * HWSZ);
    out[0] = (float)(lspec + 0.25 * lstruct);
}

// ---------------------------------------------------------------------------
extern "C" void kernel_launch(void* const* d_in, const int* in_sizes, int n_in,
                              void* d_out, int out_size, void* d_ws, size_t ws_size,
                              hipStream_t stream) {
    const float* outputs = (const float*)d_in[0];   // (4,8,512,512)
    const float* labels  = (const float*)d_in[1];   // (4,9,512,512)
    const float* inp     = (const float*)d_in[2];   // (4,9,512,512)
    const float* mtf     = (const float*)d_in[3];   // (8,1,41,41)
    const float* spec    = (const float*)d_in[4];   // (1,8,512,512)
    float* out = (float*)d_out;

    const long IMGB = (long)HWSZ;     // one image in elements
    char* ws = (char*)d_ws;
    double* acc    = (double*)ws;                    // 4 doubles
    float* panf    = (float*)(ws + 1024);            // 4 imgs fp32
    float* tmpH    = panf   + NBATCH * IMGB;         // 4 imgs
    float* da_pan8 = tmpH   + NBATCH * IMGB;         // 4 imgs
    float* saa8    = da_pan8 + NBATCH * IMGB;        // 4 imgs
    float* db_pan2 = saa8   + NBATCH * IMGB;         // 4 imgs
    float* sbb2    = db_pan2 + NBATCH * IMGB;        // 4 imgs
    float* tmpS    = sbb2   + NBATCH * IMGB;         // 8 imgs fp32
    half_t* hT     = (half_t*)(tmpS + 8 * IMGB);     // 32 imgs half (scratch)
    half_t* hDA8   = hT  + 32 * IMGB;                // 32 imgs half: da_ms (w=8)
    half_t* hDA2   = hDA8 + 32 * IMGB;               // 32 imgs half: da_out (w=2)

    hipMemsetAsync(acc, 0, 4 * sizeof(double), stream);

    // --- per-batch shared fields (fp32) ----------------------------------
    k_pan_h<<<dim3(2, 512, NBATCH), 256, 0, stream>>>(inp, mtf, tmpH);
    k_pan_v<<<dim3(2, 512, NBATCH), 256, 0, stream>>>(tmpH, mtf, panf);
    k_da<8><<<dim3(16, 16, NBATCH), 256, 0, stream>>>(panf, (long)HWSZ, da_pan8);
    k_sq<8><<<dim3(16, 16, NBATCH), 256, 0, stream>>>(da_pan8, saa8);
    k_da<2><<<dim3(16, 16, NBATCH), 256, 0, stream>>>(labels + 8 * IMGB,
                                                      (long)9 * HWSZ, db_pan2);
    k_sq<2><<<dim3(16, 16, NBATCH), 256, 0, stream>>>(db_pan2, sbb2);

    // --- L_spec ----------------------------------------------------------
    k_spec_h<<<2048, 256, 0, stream>>>(outputs, mtf, tmpS);
    k_spec_v<<<512, 256, 0, stream>>>(tmpS, labels, spec, mtf, acc);

    // --- da fields for both xcorr widths ---------------------------------
    kHbox<8><<<4096, 256, 0, stream>>>(inp, 9 * IMGB, IMGB, hT);
    kVda<8><<<1024, 256, 0, stream>>>(hT, inp, 9 * IMGB, IMGB, hDA8);   // da_ms
    kHbox<2><<<4096, 256, 0, stream>>>(outputs, 8 * IMGB, IMGB, hT);
    kVda<2><<<1024, 256, 0, stream>>>(hT, outputs, 8 * IMGB, IMGB, hDA2); // da_out

    // --- fused products + H/V box + thr + X + Y reduce -------------------
    kXfused<<<dim3(16, 16, 32), 256, 0, stream>>>(hDA8, da_pan8, saa8,
                                                  hDA2, db_pan2, sbb2, acc);

    k_final<<<1, 1, 0, stream>>>(acc, out);
}

// Round 2
// 337.989 us; speedup vs baseline: 1.0681x; 1.0681x over previous
//
#include <hip/hip_runtime.h>
#include <hip/hip_bf16.h>

// Problem constants
#define HWSZ   262144   // 512*512
#define IMG    512
#define NBATCH 4
#define NBANDS 8

typedef _Float16 half_t;
typedef _Float16 half2v __attribute__((ext_vector_type(2)));
typedef _Float16 half4v __attribute__((ext_vector_type(4)));
typedef _Float16 half8v __attribute__((ext_vector_type(8)));

// ---------------------------------------------------------------------------
// Block-level reduction: wave shuffle + LDS + one double atomic per block.
__device__ __forceinline__ void blockReduceAtomicAdd(double v, double* target,
                                                     double* red) {
    for (int off = 32; off > 0; off >>= 1) v += __shfl_down(v, off, 64);
    const int wave = threadIdx.x >> 6, lane = threadIdx.x & 63;
    if (lane == 0) red[wave] = v;
    __syncthreads();
    if (threadIdx.x == 0) atomicAdd(target, red[0] + red[1] + red[2] + red[3]);
}

// ---------------------------------------------------------------------------
// Pan smoothing (edge-pad 41x41 Gaussian, rank-1 factored), horizontal pass.
__global__ __launch_bounds__(256) void k_pan_h(const float* __restrict__ inp,
                                               const float* __restrict__ mtf,
                                               float* __restrict__ tmpH) {
    __shared__ float seg[296];
    __shared__ float vrow[41];
    const int tid = threadIdx.x;
    const int b = blockIdx.z, r = blockIdx.y, c0 = blockIdx.x * 256;
    if (tid < 41) vrow[tid] = mtf[20 * 41 + tid] / sqrtf(mtf[20 * 41 + 20]);
    const float* pan = inp + ((long)b * 9 + 8) * HWSZ + (long)r * IMG;
    for (int e = tid; e < 296; e += 256) {
        int c = c0 - 20 + e;
        c = min(max(c, 0), IMG - 1);
        seg[e] = pan[c];
    }
    __syncthreads();
    float s = 0.f;
#pragma unroll
    for (int j = 0; j < 41; ++j) s += vrow[j] * seg[tid + j];
    tmpH[(long)b * HWSZ + (long)r * IMG + c0 + tid] = s;
}

__global__ __launch_bounds__(256) void k_pan_v(const float* __restrict__ tmpH,
                                               const float* __restrict__ mtf,
                                               float* __restrict__ panf) {
    __shared__ float ucol[41];
    const int tid = threadIdx.x;
    const int b = blockIdx.z, r = blockIdx.y, c = blockIdx.x * 256 + tid;
    if (tid < 41) ucol[tid] = mtf[tid * 41 + 20] / sqrtf(mtf[20 * 41 + 20]);
    __syncthreads();
    const float* base = tmpH + (long)b * HWSZ;
    float s = 0.f;
#pragma unroll
    for (int i = 0; i < 41; ++i) {
        int rr = min(max(r - 20 + i, 0), IMG - 1);
        s += ucol[i] * base[(long)rr * IMG + c];
    }
    panf[(long)b * HWSZ + (long)r * IMG + c] = s;
}

// ---------------------------------------------------------------------------
// Small-field (4-image) helpers, LDS tile based (cheap at this size).
template <int W>
__global__ __launch_bounds__(256) void k_da(const float* __restrict__ in,
                                            long inBatchStride,
                                            float* __restrict__ out) {
    constexpr int TS = 32, WIN = 2 * W, NN = 4 * W * W, RE = TS + WIN - 1;
    constexpr int SR = RE;
    constexpr int ST = 33;
    __shared__ float RAW[RE * SR];
    __shared__ float T[RE * ST];
    const int tid = threadIdx.x;
    const int tr0 = blockIdx.y * TS, tc0 = blockIdx.x * TS;
    const float* src = in + (long)blockIdx.z * inBatchStride;
    for (int e = tid; e < RE * RE; e += 256) {
        int r = e / RE, c = e % RE;
        int gr = tr0 - (W - 1) + r, gc = tc0 - (W - 1) + c;
        float v = 0.f;
        if (gr >= 0 && gr < IMG && gc >= 0 && gc < IMG) v = src[(long)gr * IMG + gc];
        RAW[r * SR + c] = v;
    }
    __syncthreads();
    for (int e = tid; e < RE * TS; e += 256) {
        int r = e >> 5, j = e & 31;
        float s = 0.f;
#pragma unroll
        for (int k = 0; k < WIN; ++k) s += RAW[r * SR + j + k];
        T[r * ST + j] = s;
    }
    __syncthreads();
    float* dst = out + (long)blockIdx.z * HWSZ;
    for (int e = tid; e < TS * TS; e += 256) {
        int pr = e >> 5, pc = e & 31;
        float s = 0.f;
#pragma unroll
        for (int k = 0; k < WIN; ++k) s += T[(pr + k) * ST + pc];
        float da = RAW[(pr + W - 1) * SR + (pc + W - 1)] - s * (1.0f / NN);
        dst[(long)(tr0 + pr) * IMG + tc0 + pc] = da;
    }
}

// k_sq now writes its output TRANSPOSED (outT[c][r] = box(in^2)(r,c)) so the
// final xcorr kernel can read it contiguously. pr is lane-contiguous in the
// write loop -> coalesced; T read stride ST=33 -> conflict-free.
template <int W>
__global__ __launch_bounds__(256) void k_sq(const float* __restrict__ in,
                                            float* __restrict__ outT) {
    constexpr int TS = 32, WIN = 2 * W, RE = TS + WIN - 1;
    constexpr int SR = RE, ST = 33;
    __shared__ float RAW[RE * SR];
    __shared__ float T[RE * ST];
    const int tid = threadIdx.x;
    const int tr0 = blockIdx.y * TS, tc0 = blockIdx.x * TS;
    const float* src = in + (long)blockIdx.z * HWSZ;
    for (int e = tid; e < RE * RE; e += 256) {
        int r = e / RE, c = e % RE;
        int gr = tr0 - (W - 1) + r, gc = tc0 - (W - 1) + c;
        float v = 0.f;
        if (gr >= 0 && gr < IMG && gc >= 0 && gc < IMG) v = src[(long)gr * IMG + gc];
        RAW[r * SR + c] = v;
    }
    __syncthreads();
    for (int e = tid; e < RE * TS; e += 256) {
        int r = e >> 5, j = e & 31;
        float s = 0.f;
#pragma unroll
        for (int k = 0; k < WIN; ++k) {
            float v = RAW[r * SR + j + k];
            s += v * v;
        }
        T[r * ST + j] = s;
    }
    __syncthreads();
    float* dst = outT + (long)blockIdx.z * HWSZ;
    for (int e = tid; e < TS * TS; e += 256) {
        int pc = e >> 5, pr = e & 31;               // pr contiguous per lane
        float s = 0.f;
#pragma unroll
        for (int k = 0; k < WIN; ++k) s += T[(pr + k) * ST + pc];
        dst[(long)(tc0 + pc) * IMG + tr0 + pr] = s; // transposed write
    }
}

// ---------------------------------------------------------------------------
// Full-size (32-image) separable box passes, zero LDS, register sliding.
// Intermediates fp16 (t, da, products). Error budget: thr/X err ~2e-3,
// loss err ~1e-3 << 1.3e-2 threshold (measured absmax 0.0 at fp16).

template <int W> struct WinDims {
    static constexpr int A  = (W + 3) & ~3;
    static constexpr int NU = A + W + 8;              // elements actually used
    static constexpr int NF = (NU + 3) / 4;           // 4-elem chunks loaded
    static constexpr int NV = NF * 4;                 // padded array size
};

template <int W>
__device__ __forceinline__ void loadRowWin(const float* __restrict__ row, int c0,
                                           float* v) {
    constexpr int A = WinDims<W>::A;
    constexpr int NF = WinDims<W>::NF;
#pragma unroll
    for (int f = 0; f < NF; ++f) {
        const int cb = c0 - A + 4 * f;
        if (cb >= 0 && cb + 3 < IMG) {
            const float4 t = *(const float4*)(row + cb);
            v[4 * f + 0] = t.x; v[4 * f + 1] = t.y;
            v[4 * f + 2] = t.z; v[4 * f + 3] = t.w;
        } else {
#pragma unroll
            for (int u = 0; u < 4; ++u) {
                const int c = cb + u;
                v[4 * f + u] = (c >= 0 && c < IMG) ? row[c] : 0.f;
            }
        }
    }
}

template <int W>
__device__ __forceinline__ void loadRowWinH(const half_t* __restrict__ row, int c0,
                                            float* v) {
    constexpr int A = WinDims<W>::A;
    constexpr int NF = WinDims<W>::NF;
#pragma unroll
    for (int f = 0; f < NF; ++f) {
        const int cb = c0 - A + 4 * f;   // multiple of 4 -> 8B aligned
        if (cb >= 0 && cb + 3 < IMG) {
            const half4v t = *(const half4v*)(row + cb);
            v[4 * f + 0] = (float)t[0]; v[4 * f + 1] = (float)t[1];
            v[4 * f + 2] = (float)t[2]; v[4 * f + 3] = (float)t[3];
        } else {
#pragma unroll
            for (int u = 0; u < 4; ++u) {
                const int c = cb + u;
                v[4 * f + u] = (c >= 0 && c < IMG) ? (float)row[c] : 0.f;
            }
        }
    }
}

// H box of a raw fp32 input field -> t (half, z*HWSZ layout). grid 4096 x 256.
template <int W>
__global__ __launch_bounds__(256) void kHbox(const float* __restrict__ in,
                                             long sB, long sC,
                                             half_t* __restrict__ out) {
    constexpr int A = WinDims<W>::A;
    const int g = blockIdx.x * 256 + threadIdx.x;
    const int c0 = (g & 63) << 3, r = (g >> 6) & 511, z = g >> 15;
    const float* row = in + (long)(z >> 3) * sB + (long)(z & 7) * sC + (long)r * IMG;
    float v[WinDims<W>::NV];
    loadRowWin<W>(row, c0, v);
    float o[8];
    float s = 0.f;
#pragma unroll
    for (int i = A - W + 1; i <= A + W; ++i) s += v[i];
    o[0] = s;
#pragma unroll
    for (int j = 1; j < 8; ++j) {
        s += v[A + W + j] - v[A - W + j];
        o[j] = s;
    }
    half8v h;
#pragma unroll
    for (int j = 0; j < 8; ++j) h[j] = (half_t)o[j];
    *(half8v*)(out + (long)z * HWSZ + (long)r * IMG + c0) = h;   // 16B aligned
}

// V box of t (half) + epilogue da = orig - box/n (half out).
// 2 columns/thread via half2/float2 loads. grid 1024 x 256.
template <int W>
__global__ __launch_bounds__(256) void kVda(const half_t* __restrict__ t,
                                            const float* __restrict__ orig,
                                            long sB, long sC,
                                            half_t* __restrict__ out) {
    constexpr int NR = 2 * W + 15, NN = 4 * W * W;
    const int g = blockIdx.x * 256 + threadIdx.x;
    const int cp = (g & 255) * 2;          // even column pair base
    const int rc = (g >> 8) & 31, z = g >> 13;
    const int r0 = rc * 16;
    const half_t* tz = t + (long)z * HWSZ + cp;
    float vx[NR], vy[NR];
#pragma unroll
    for (int i = 0; i < NR; ++i) {
        const int rr = r0 - W + 1 + i;
        if (rr >= 0 && rr < IMG) {
            const half2v h = *(const half2v*)(tz + (long)rr * IMG);
            vx[i] = (float)h[0]; vy[i] = (float)h[1];
        } else { vx[i] = 0.f; vy[i] = 0.f; }
    }
    const float* oz = orig + (long)(z >> 3) * sB + (long)(z & 7) * sC + cp;
    half_t* dst = out + (long)z * HWSZ + cp;
    float sx = 0.f, sy = 0.f;
#pragma unroll
    for (int i = 0; i < 2 * W; ++i) { sx += vx[i]; sy += vy[i]; }
#pragma unroll
    for (int j = 0; j < 16; ++j) {
        const float2 o = *(const float2*)(oz + (long)(r0 + j) * IMG);
        half2v h;
        h[0] = (half_t)(o.x - sx * (1.0f / NN));
        h[1] = (half_t)(o.y - sy * (1.0f / NN));
        *(half2v*)(dst + (long)(r0 + j) * IMG) = h;
        if (j < 15) {
            sx += vx[2 * W + j] - vx[j];
            sy += vy[2 * W + j] - vy[j];
        }
    }
}

// ---------------------------------------------------------------------------
// H box of (da*dshared) and (da*da), written TRANSPOSED: oT[z][c][r].
// Per-thread sliding H-box (same math as old kHprod), 64x64 tile staged
// through one float LDS buffer (pitch 65: store lanes r0..7/cg0..7 and
// gather lanes 2-way max -> conflict-free), coalesced half8 global writes
// along the original-row axis. grid (8,8,32) x 256.
template <int W>
__global__ __launch_bounds__(256) void kHprodT(const half_t* __restrict__ da,
                                               const float* __restrict__ dsh,
                                               half_t* __restrict__ o1T,
                                               half_t* __restrict__ o2T) {
    constexpr int A = WinDims<W>::A;
    constexpr int NU = WinDims<W>::NU;
    constexpr int NV = WinDims<W>::NV;
    constexpr int LP = 65;                        // float pitch, conflict-free
    __shared__ float L[64 * LP];
    const int tid = threadIdx.x;
    const int z = blockIdx.z;
    const int tr0 = blockIdx.y * 64, tc0 = blockIdx.x * 64;
    const half_t* daz = da + (long)z * HWSZ;
    const float* dsz = dsh + (long)(z >> 3) * HWSZ;

    float a[2][8], bb[2][8];
#pragma unroll
    for (int u = 0; u < 2; ++u) {
        const int unit = tid + 256 * u;
        const int r = unit >> 3, cg = unit & 7;
        const int gr = tr0 + r, c0 = tc0 + cg * 8;
        float va[NV], vs[NV];
        loadRowWinH<W>(daz + (long)gr * IMG, c0, va);
        loadRowWin<W>(dsz + (long)gr * IMG, c0, vs);
        float p1[NV], p2[NV];
#pragma unroll
        for (int i = 0; i < NU; ++i) { p1[i] = va[i] * vs[i]; p2[i] = va[i] * va[i]; }
        float s1 = 0.f, s2 = 0.f;
#pragma unroll
        for (int i = A - W + 1; i <= A + W; ++i) { s1 += p1[i]; s2 += p2[i]; }
        a[u][0] = s1; bb[u][0] = s2;
#pragma unroll
        for (int j = 1; j < 8; ++j) {
            s1 += p1[A + W + j] - p1[A - W + j];
            s2 += p2[A + W + j] - p2[A - W + j];
            a[u][j] = s1; bb[u][j] = s2;
        }
    }
    const long zbase = (long)z * HWSZ + tr0;
    // round 1: a -> o1T
#pragma unroll
    for (int u = 0; u < 2; ++u) {
        const int unit = tid + 256 * u;
        const int r = unit >> 3, cg = unit & 7;
#pragma unroll
        for (int j = 0; j < 8; ++j) L[r * LP + cg * 8 + j] = a[u][j];
    }
    __syncthreads();
#pragma unroll
    for (int u = 0; u < 2; ++u) {
        const int e = tid + 256 * u;
        const int c = e >> 3, r0 = (e & 7) * 8;
        half8v h;
#pragma unroll
        for (int j = 0; j < 8; ++j) h[j] = (half_t)L[(r0 + j) * LP + c];
        *(half8v*)(o1T + zbase + (long)(tc0 + c) * IMG + r0) = h;
    }
    __syncthreads();
    // round 2: bb -> o2T
#pragma unroll
    for (int u = 0; u < 2; ++u) {
        const int unit = tid + 256 * u;
        const int r = unit >> 3, cg = unit & 7;
#pragma unroll
        for (int j = 0; j < 8; ++j) L[r * LP + cg * 8 + j] = bb[u][j];
    }
    __syncthreads();
#pragma unroll
    for (int u = 0; u < 2; ++u) {
        const int e = tid + 256 * u;
        const int c = e >> 3, r0 = (e & 7) * 8;
        half8v h;
#pragma unroll
        for (int j = 0; j < 8; ++j) h[j] = (half_t)L[(r0 + j) * LP + c];
        *(half8v*)(o2T + zbase + (long)(tc0 + c) * IMG + r0) = h;
    }
}

// ---------------------------------------------------------------------------
// Final xcorr kernel on TRANSPOSED arrays: the original V-box is now an
// H-box -> all loads contiguous + vectorized. 8 outputs/thread, sliding
// window, same arithmetic as the verified kVfinBoth. grid 4096 x 256.
__global__ __launch_bounds__(256) void kVfinT(const half_t* __restrict__ p1,
                                              const half_t* __restrict__ p2,
                                              const float* __restrict__ saaT,
                                              const half_t* __restrict__ q1,
                                              const half_t* __restrict__ q2,
                                              const float* __restrict__ sbbT,
                                              double* __restrict__ acc) {
    __shared__ double red[4];
    const int g = blockIdx.x * 256 + threadIdx.x;
    const int c0 = (g & 63) << 3;     // original row (contiguous axis), 8/thread
    const int rt = (g >> 6) & 511;    // original col
    const int z = g >> 15;
    const long rowoff = (long)z * HWSZ + (long)rt * IMG;
    const long soff = (long)(z >> 3) * HWSZ + (long)rt * IMG + c0;

    float thrv[8];
    {   // ---- w=8: thr = 1 - sab/(sqrt(saa*s_ms)+eps)
        constexpr int W = 8;
        constexpr int A = WinDims<W>::A;
        float v1[WinDims<W>::NV], v2[WinDims<W>::NV];
        loadRowWinH<W>(p1 + rowoff, c0, v1);
        loadRowWinH<W>(p2 + rowoff, c0, v2);
        const float4 sa0 = *(const float4*)(saaT + soff);
        const float4 sa1 = *(const float4*)(saaT + soff + 4);
        const float sa[8] = {sa0.x, sa0.y, sa0.z, sa0.w,
                             sa1.x, sa1.y, sa1.z, sa1.w};
        float s1 = 0.f, s2 = 0.f;
#pragma unroll
        for (int i = A - W + 1; i <= A + W; ++i) { s1 += v1[i]; s2 += v2[i]; }
#pragma unroll
        for (int j = 0; j < 8; ++j) {
            const float den = sqrtf(fmaxf(sa[j] * s2, 0.f)) + 1e-20f;
            thrv[j] = 1.0f - s1 / den;
            if (j < 7) {
                s1 += v1[A + W + 1 + j] - v1[A - W + 1 + j];
                s2 += v2[A + W + 1 + j] - v2[A - W + 1 + j];
            }
        }
    }
    double ysum = 0.0;
    {   // ---- w=2: X vs thr, accumulate Y
        constexpr int W = 2;
        constexpr int A = WinDims<W>::A;
        float v1[WinDims<W>::NV], v2[WinDims<W>::NV];
        loadRowWinH<W>(q1 + rowoff, c0, v1);
        loadRowWinH<W>(q2 + rowoff, c0, v2);
        const float4 sb0 = *(const float4*)(sbbT + soff);
        const float4 sb1 = *(const float4*)(sbbT + soff + 4);
        const float sb[8] = {sb0.x, sb0.y, sb0.z, sb0.w,
                             sb1.x, sb1.y, sb1.z, sb1.w};
        float s1 = 0.f, s2 = 0.f;
#pragma unroll
        for (int i = A - W + 1; i <= A + W; ++i) { s1 += v1[i]; s2 += v2[i]; }
#pragma unroll
        for (int j = 0; j < 8; ++j) {
            const float den = sqrtf(fmaxf(s2 * sb[j], 0.f)) + 1e-20f;
            const float Xc = s1 / den;
            const float X = 1.0f - fmaxf(Xc, -1.0f);
            if (X > thrv[j]) ysum += (double)X;
            if (j < 7) {
                s1 += v1[A + W + 1 + j] - v1[A - W + 1 + j];
                s2 += v2[A + W + 1 + j] - v2[A - W + 1 + j];
            }
        }
    }
    blockReduceAtomicAdd(ysum, acc + 2, red);
}

// ---------------------------------------------------------------------------
// L_spec: strided MTF conv of outputs (rank-1 factored), H then V+reduce.
__global__ __launch_bounds__(256) void k_spec_h(const float* __restrict__ outputs,
                                                const float* __restrict__ mtf,
                                                float* __restrict__ tmpS) {
    __shared__ float vrow[41];
    const int g = blockIdx.x * 256 + threadIdx.x;
    const int q = g & 31, r = (g >> 5) & 511, z = g >> 14;   // z uniform/block
    const int band = z & 7;
    if (threadIdx.x < 41)
        vrow[threadIdx.x] = mtf[band * 1681 + 20 * 41 + threadIdx.x] /
                            sqrtf(mtf[band * 1681 + 20 * 41 + 20]);
    __syncthreads();
    const float* row = outputs + (long)z * HWSZ + (long)r * IMG;
    float v[56];
#pragma unroll
    for (int f = 0; f < 14; ++f) {
        const int cb = 16 * q - 20 + 4 * f;
        if (cb >= 0 && cb + 3 < IMG) {
            const float4 t = *(const float4*)(row + cb);
            v[4 * f + 0] = t.x; v[4 * f + 1] = t.y;
            v[4 * f + 2] = t.z; v[4 * f + 3] = t.w;
        } else {
#pragma unroll
            for (int u = 0; u < 4; ++u) {
                const int cc = cb + u;
                v[4 * f + u] = (cc >= 0 && cc < IMG) ? row[cc] : 0.f;
            }
        }
    }
    float o[4] = {0.f, 0.f, 0.f, 0.f};
#pragma unroll
    for (int j = 0; j < 41; ++j) {
        const float w = vrow[j];
#pragma unroll
        for (int u = 0; u < 4; ++u) o[u] += w * v[2 + 4 * u + j];
    }
    float* dst = tmpS + ((long)z * IMG + r) * 128 + 4 * q;
    *(float4*)dst = make_float4(o[0], o[1], o[2], o[3]);
}

__global__ __launch_bounds__(256) void k_spec_v(const float* __restrict__ tmpS,
                                                const float* __restrict__ labels,
                                                const float* __restrict__ spec,
                                                const float* __restrict__ mtf,
                                                double* __restrict__ acc) {
    __shared__ double redT[4];
    __shared__ double redM[4];
    __shared__ float ucol[41];
    const int g = blockIdx.x * 256 + threadIdx.x;
    const int q = g & 31, rs = (g >> 5) & 127, z = g >> 12;   // z uniform/block
    const int b = z >> 3, band = z & 7;
    if (threadIdx.x < 41)
        ucol[threadIdx.x] = mtf[band * 1681 + threadIdx.x * 41 + 20] /
                            sqrtf(mtf[band * 1681 + 20 * 41 + 20]);
    __syncthreads();
    const float* base = tmpS + (long)z * IMG * 128 + 4 * q;
    const int rbase = 4 * rs - 18;
    float o[4] = {0.f, 0.f, 0.f, 0.f};
    if (rbase >= 0 && rbase + 40 < IMG) {
#pragma unroll
        for (int i = 0; i < 41; ++i) {
            const float4 v = *(const float4*)(base + (long)(rbase + i) * 128);
            const float w = ucol[i];
            o[0] += w * v.x; o[1] += w * v.y; o[2] += w * v.z; o[3] += w * v.w;
        }
    } else {
        for (int i = 0; i < 41; ++i) {
            const int r = rbase + i;
            if (r >= 0 && r < IMG) {
                const float4 v = *(const float4*)(base + (long)r * 128);
                const float w = ucol[i];
                o[0] += w * v.x; o[1] += w * v.y; o[2] += w * v.z; o[3] += w * v.w;
            }
        }
    }
    const int gr = 2 + 4 * rs;
    float tsum = 0.f, msum = 0.f;
#pragma unroll
    for (int u = 0; u < 4; ++u) {
        const int gc = 2 + 4 * (4 * q + u);
        const float m = spec[(long)band * HWSZ + (long)gr * IMG + gc];
        const float y = labels[((long)b * 9 + band) * HWSZ + (long)gr * IMG + gc];
        tsum += fabsf(o[u] * m - y * m);
        msum += m;
    }
    blockReduceAtomicAdd((double)tsum, acc + 0, redT);
    blockReduceAtomicAdd((double)msum, acc + 1, redM);
}

__global__ void k_final(const double* __restrict__ acc, float* __restrict__ out) {
    double lspec = acc[0] / acc[1];
    double lstruct = acc[2] / (double)(NBATCH * NBANDS * HWSZ);
    out[0] = (float)(lspec + 0.25 * lstruct);
}

// ---------------------------------------------------------------------------
extern "C" void kernel_launch(void* const* d_in, const int* in_sizes, int n_in,
                              void* d_out, int out_size, void* d_ws, size_t ws_size,
                              hipStream_t stream) {
    const float* outputs = (const float*)d_in[0];   // (4,8,512,512)
    const float* labels  = (const float*)d_in[1];   // (4,9,512,512)
    const float* inp     = (const float*)d_in[2];   // (4,9,512,512)
    const float* mtf     = (const float*)d_in[3];   // (8,1,41,41)
    const float* spec    = (const float*)d_in[4];   // (1,8,512,512)
    float* out = (float*)d_out;

    const long IMGB = (long)HWSZ;     // one image in elements
    char* ws = (char*)d_ws;
    double* acc    = (double*)ws;                    // 4 doubles
    float* panf    = (float*)(ws + 1024);            // 4 imgs fp32
    float* tmpH    = panf   + NBATCH * IMGB;         // 4 imgs
    float* da_pan8 = tmpH   + NBATCH * IMGB;         // 4 imgs
    float* saaT    = da_pan8 + NBATCH * IMGB;        // 4 imgs (transposed)
    float* db_pan2 = saaT   + NBATCH * IMGB;         // 4 imgs
    float* sbbT    = db_pan2 + NBATCH * IMGB;        // 4 imgs (transposed)
    float* tmpS    = sbbT   + NBATCH * IMGB;         // 8 imgs fp32
    half_t* hT     = (half_t*)(tmpS + 8 * IMGB);     // 32 imgs half (scratch)
    half_t* hDA8   = hT  + 32 * IMGB;                // 32 imgs half: da_ms (w=8)
    half_t* hDA2   = hDA8 + 32 * IMGB;               // 32 imgs half: da_out (w=2)
    half_t* hP1T   = hDA2 + 32 * IMGB;               // 32 imgs half (transposed)
    half_t* hP2T   = hP1T + 32 * IMGB;               // 32 imgs half (transposed)
    half_t* hQ1T   = hDA8;   // alias: hDA8 dead after kHprodT<8>
    half_t* hQ2T   = hT;     // alias: hT dead after kVda<2>

    hipMemsetAsync(acc, 0, 4 * sizeof(double), stream);

    // --- per-batch shared fields (fp32) ----------------------------------
    k_pan_h<<<dim3(2, 512, NBATCH), 256, 0, stream>>>(inp, mtf, tmpH);
    k_pan_v<<<dim3(2, 512, NBATCH), 256, 0, stream>>>(tmpH, mtf, panf);
    k_da<8><<<dim3(16, 16, NBATCH), 256, 0, stream>>>(panf, (long)HWSZ, da_pan8);
    k_sq<8><<<dim3(16, 16, NBATCH), 256, 0, stream>>>(da_pan8, saaT);
    k_da<2><<<dim3(16, 16, NBATCH), 256, 0, stream>>>(labels + 8 * IMGB,
                                                      (long)9 * HWSZ, db_pan2);
    k_sq<2><<<dim3(16, 16, NBATCH), 256, 0, stream>>>(db_pan2, sbbT);

    // --- L_spec ----------------------------------------------------------
    k_spec_h<<<2048, 256, 0, stream>>>(outputs, mtf, tmpS);
    k_spec_v<<<512, 256, 0, stream>>>(tmpS, labels, spec, mtf, acc);

    // --- w=8 pipeline ----------------------------------------------------
    kHbox<8><<<4096, 256, 0, stream>>>(inp, 9 * IMGB, IMGB, hT);
    kVda<8><<<1024, 256, 0, stream>>>(hT, inp, 9 * IMGB, IMGB, hDA8);   // da_ms
    kHprodT<8><<<dim3(8, 8, 32), 256, 0, stream>>>(hDA8, da_pan8, hP1T, hP2T);

    // --- w=2 pipeline ----------------------------------------------------
    kHbox<2><<<4096, 256, 0, stream>>>(outputs, 8 * IMGB, IMGB, hT);
    kVda<2><<<1024, 256, 0, stream>>>(hT, outputs, 8 * IMGB, IMGB, hDA2); // da_out
    kHprodT<2><<<dim3(8, 8, 32), 256, 0, stream>>>(hDA2, db_pan2, hQ1T, hQ2T);

    // --- final: thr, X, Y reduce (all reads contiguous) ------------------
    kVfinT<<<4096, 256, 0, stream>>>(hP1T, hP2T, saaT, hQ1T, hQ2T, sbbT, acc);

    k_final<<<1, 1, 0, stream>>>(acc, out);
}

// Round 3
// 312.772 us; speedup vs baseline: 1.1542x; 1.0806x over previous
//
#include <hip/hip_runtime.h>
#include <hip/hip_bf16.h>

// Problem constants
#define HWSZ   262144   // 512*512
#define IMG    512
#define NBATCH 4
#define NBANDS 8

typedef _Float16 half_t;
typedef _Float16 half2v __attribute__((ext_vector_type(2)));
typedef _Float16 half4v __attribute__((ext_vector_type(4)));
typedef _Float16 half8v __attribute__((ext_vector_type(8)));

// ---------------------------------------------------------------------------
// Block-level reduction: wave shuffle + LDS + one double atomic per block.
__device__ __forceinline__ void blockReduceAtomicAdd(double v, double* target,
                                                     double* red) {
    for (int off = 32; off > 0; off >>= 1) v += __shfl_down(v, off, 64);
    const int wave = threadIdx.x >> 6, lane = threadIdx.x & 63;
    if (lane == 0) red[wave] = v;
    __syncthreads();
    if (threadIdx.x == 0) atomicAdd(target, red[0] + red[1] + red[2] + red[3]);
}

// ---------------------------------------------------------------------------
// Pan smoothing (edge-pad 41x41 Gaussian, rank-1 factored), horizontal pass.
__global__ __launch_bounds__(256) void k_pan_h(const float* __restrict__ inp,
                                               const float* __restrict__ mtf,
                                               float* __restrict__ tmpH) {
    __shared__ float seg[296];
    __shared__ float vrow[41];
    const int tid = threadIdx.x;
    const int b = blockIdx.z, r = blockIdx.y, c0 = blockIdx.x * 256;
    if (tid < 41) vrow[tid] = mtf[20 * 41 + tid] / sqrtf(mtf[20 * 41 + 20]);
    const float* pan = inp + ((long)b * 9 + 8) * HWSZ + (long)r * IMG;
    for (int e = tid; e < 296; e += 256) {
        int c = c0 - 20 + e;
        c = min(max(c, 0), IMG - 1);
        seg[e] = pan[c];
    }
    __syncthreads();
    float s = 0.f;
#pragma unroll
    for (int j = 0; j < 41; ++j) s += vrow[j] * seg[tid + j];
    tmpH[(long)b * HWSZ + (long)r * IMG + c0 + tid] = s;
}

__global__ __launch_bounds__(256) void k_pan_v(const float* __restrict__ tmpH,
                                               const float* __restrict__ mtf,
                                               float* __restrict__ panf) {
    __shared__ float ucol[41];
    const int tid = threadIdx.x;
    const int b = blockIdx.z, r = blockIdx.y, c = blockIdx.x * 256 + tid;
    if (tid < 41) ucol[tid] = mtf[tid * 41 + 20] / sqrtf(mtf[20 * 41 + 20]);
    __syncthreads();
    const float* base = tmpH + (long)b * HWSZ;
    float s = 0.f;
#pragma unroll
    for (int i = 0; i < 41; ++i) {
        int rr = min(max(r - 20 + i, 0), IMG - 1);
        s += ucol[i] * base[(long)rr * IMG + c];
    }
    panf[(long)b * HWSZ + (long)r * IMG + c] = s;
}

// ---------------------------------------------------------------------------
// Small-field (4-image) helpers, LDS tile based (cheap at this size).
template <int W>
__global__ __launch_bounds__(256) void k_da(const float* __restrict__ in,
                                            long inBatchStride,
                                            float* __restrict__ out) {
    constexpr int TS = 32, WIN = 2 * W, NN = 4 * W * W, RE = TS + WIN - 1;
    constexpr int SR = RE;
    constexpr int ST = 33;
    __shared__ float RAW[RE * SR];
    __shared__ float T[RE * ST];
    const int tid = threadIdx.x;
    const int tr0 = blockIdx.y * TS, tc0 = blockIdx.x * TS;
    const float* src = in + (long)blockIdx.z * inBatchStride;
    for (int e = tid; e < RE * RE; e += 256) {
        int r = e / RE, c = e % RE;
        int gr = tr0 - (W - 1) + r, gc = tc0 - (W - 1) + c;
        float v = 0.f;
        if (gr >= 0 && gr < IMG && gc >= 0 && gc < IMG) v = src[(long)gr * IMG + gc];
        RAW[r * SR + c] = v;
    }
    __syncthreads();
    for (int e = tid; e < RE * TS; e += 256) {
        int r = e >> 5, j = e & 31;
        float s = 0.f;
#pragma unroll
        for (int k = 0; k < WIN; ++k) s += RAW[r * SR + j + k];
        T[r * ST + j] = s;
    }
    __syncthreads();
    float* dst = out + (long)blockIdx.z * HWSZ;
    for (int e = tid; e < TS * TS; e += 256) {
        int pr = e >> 5, pc = e & 31;
        float s = 0.f;
#pragma unroll
        for (int k = 0; k < WIN; ++k) s += T[(pr + k) * ST + pc];
        float da = RAW[(pr + W - 1) * SR + (pc + W - 1)] - s * (1.0f / NN);
        dst[(long)(tr0 + pr) * IMG + tc0 + pc] = da;
    }
}

template <int W>
__global__ __launch_bounds__(256) void k_sq(const float* __restrict__ in,
                                            float* __restrict__ out) {
    constexpr int TS = 32, WIN = 2 * W, RE = TS + WIN - 1;
    constexpr int SR = RE, ST = 33;
    __shared__ float RAW[RE * SR];
    __shared__ float T[RE * ST];
    const int tid = threadIdx.x;
    const int tr0 = blockIdx.y * TS, tc0 = blockIdx.x * TS;
    const float* src = in + (long)blockIdx.z * HWSZ;
    for (int e = tid; e < RE * RE; e += 256) {
        int r = e / RE, c = e % RE;
        int gr = tr0 - (W - 1) + r, gc = tc0 - (W - 1) + c;
        float v = 0.f;
        if (gr >= 0 && gr < IMG && gc >= 0 && gc < IMG) v = src[(long)gr * IMG + gc];
        RAW[r * SR + c] = v;
    }
    __syncthreads();
    for (int e = tid; e < RE * TS; e += 256) {
        int r = e >> 5, j = e & 31;
        float s = 0.f;
#pragma unroll
        for (int k = 0; k < WIN; ++k) {
            float v = RAW[r * SR + j + k];
            s += v * v;
        }
        T[r * ST + j] = s;
    }
    __syncthreads();
    float* dst = out + (long)blockIdx.z * HWSZ;
    for (int e = tid; e < TS * TS; e += 256) {
        int pr = e >> 5, pc = e & 31;
        float s = 0.f;
#pragma unroll
        for (int k = 0; k < WIN; ++k) s += T[(pr + k) * ST + pc];
        dst[(long)(tr0 + pr) * IMG + tc0 + pc] = s;
    }
}

// ---------------------------------------------------------------------------
// Full-size (32-image) separable box passes, zero LDS, register sliding.
// Intermediates fp16 (t, da, products). Error budget: thr/X err ~2e-3,
// loss err ~1e-3 << 1.3e-2 threshold (measured absmax 0.0 at fp16).

template <int W> struct WinDims {
    static constexpr int A  = (W + 3) & ~3;
    static constexpr int NU = A + W + 8;              // elements actually used
    static constexpr int NF = (NU + 3) / 4;           // 4-elem chunks loaded
    static constexpr int NV = NF * 4;                 // padded array size
};

template <int W>
__device__ __forceinline__ void loadRowWin(const float* __restrict__ row, int c0,
                                           float* v) {
    constexpr int A = WinDims<W>::A;
    constexpr int NF = WinDims<W>::NF;
#pragma unroll
    for (int f = 0; f < NF; ++f) {
        const int cb = c0 - A + 4 * f;
        if (cb >= 0 && cb + 3 < IMG) {
            const float4 t = *(const float4*)(row + cb);
            v[4 * f + 0] = t.x; v[4 * f + 1] = t.y;
            v[4 * f + 2] = t.z; v[4 * f + 3] = t.w;
        } else {
#pragma unroll
            for (int u = 0; u < 4; ++u) {
                const int c = cb + u;
                v[4 * f + u] = (c >= 0 && c < IMG) ? row[c] : 0.f;
            }
        }
    }
}

template <int W>
__device__ __forceinline__ void loadRowWinH(const half_t* __restrict__ row, int c0,
                                            float* v) {
    constexpr int A = WinDims<W>::A;
    constexpr int NF = WinDims<W>::NF;
#pragma unroll
    for (int f = 0; f < NF; ++f) {
        const int cb = c0 - A + 4 * f;   // multiple of 4 -> 8B aligned
        if (cb >= 0 && cb + 3 < IMG) {
            const half4v t = *(const half4v*)(row + cb);
            v[4 * f + 0] = (float)t[0]; v[4 * f + 1] = (float)t[1];
            v[4 * f + 2] = (float)t[2]; v[4 * f + 3] = (float)t[3];
        } else {
#pragma unroll
            for (int u = 0; u < 4; ++u) {
                const int c = cb + u;
                v[4 * f + u] = (c >= 0 && c < IMG) ? (float)row[c] : 0.f;
            }
        }
    }
}

// H box of a raw fp32 input field -> t (half, z*HWSZ layout). grid 4096 x 256.
template <int W>
__global__ __launch_bounds__(256) void kHbox(const float* __restrict__ in,
                                             long sB, long sC,
                                             half_t* __restrict__ out) {
    constexpr int A = WinDims<W>::A;
    const int g = blockIdx.x * 256 + threadIdx.x;
    const int c0 = (g & 63) << 3, r = (g >> 6) & 511, z = g >> 15;
    const float* row = in + (long)(z >> 3) * sB + (long)(z & 7) * sC + (long)r * IMG;
    float v[WinDims<W>::NV];
    loadRowWin<W>(row, c0, v);
    float o[8];
    float s = 0.f;
#pragma unroll
    for (int i = A - W + 1; i <= A + W; ++i) s += v[i];
    o[0] = s;
#pragma unroll
    for (int j = 1; j < 8; ++j) {
        s += v[A + W + j] - v[A - W + j];
        o[j] = s;
    }
    half8v h;
#pragma unroll
    for (int j = 0; j < 8; ++j) h[j] = (half_t)o[j];
    *(half8v*)(out + (long)z * HWSZ + (long)r * IMG + c0) = h;   // 16B aligned
}

// V box of t (half) + epilogue da = orig - box/n (half out).
// 2 columns/thread via half2/float2 loads. grid 1024 x 256.
template <int W>
__global__ __launch_bounds__(256) void kVda(const half_t* __restrict__ t,
                                            const float* __restrict__ orig,
                                            long sB, long sC,
                                            half_t* __restrict__ out) {
    constexpr int NR = 2 * W + 15, NN = 4 * W * W;
    const int g = blockIdx.x * 256 + threadIdx.x;
    const int cp = (g & 255) * 2;          // even column pair base
    const int rc = (g >> 8) & 31, z = g >> 13;
    const int r0 = rc * 16;
    const half_t* tz = t + (long)z * HWSZ + cp;
    float vx[NR], vy[NR];
#pragma unroll
    for (int i = 0; i < NR; ++i) {
        const int rr = r0 - W + 1 + i;
        if (rr >= 0 && rr < IMG) {
            const half2v h = *(const half2v*)(tz + (long)rr * IMG);
            vx[i] = (float)h[0]; vy[i] = (float)h[1];
        } else { vx[i] = 0.f; vy[i] = 0.f; }
    }
    const float* oz = orig + (long)(z >> 3) * sB + (long)(z & 7) * sC + cp;
    half_t* dst = out + (long)z * HWSZ + cp;
    float sx = 0.f, sy = 0.f;
#pragma unroll
    for (int i = 0; i < 2 * W; ++i) { sx += vx[i]; sy += vy[i]; }
#pragma unroll
    for (int j = 0; j < 16; ++j) {
        const float2 o = *(const float2*)(oz + (long)(r0 + j) * IMG);
        half2v h;
        h[0] = (half_t)(o.x - sx * (1.0f / NN));
        h[1] = (half_t)(o.y - sy * (1.0f / NN));
        *(half2v*)(dst + (long)(r0 + j) * IMG) = h;
        if (j < 15) {
            sx += vx[2 * W + j] - vx[j];
            sy += vy[2 * W + j] - vy[j];
        }
    }
}

// ---------------------------------------------------------------------------
// Fused product + H-box + V-box. Per 64x64 output tile: stage H-box product
// rows (per-thread sliding window, same math as the verified kHprodT) into
// LDS as packed half2(p1,p2); one sync; V-box via register sliding down
// columns (2 LDS reads + 4 adds per output). Eliminates the 64 MB product
// write + 72 MB latency-exposed read of the old 3-kernel chain.
// All LDS patterns <=2-way bank aliasing (free). LDS: (63+2W)*65*4 bytes.

template <int W>
__device__ __forceinline__ void stageProducts(const half_t* __restrict__ daz,
                                              const float* __restrict__ dsz,
                                              int tr0, int tc0,
                                              unsigned int* L) {
    constexpr int A = WinDims<W>::A;
    constexpr int NU = WinDims<W>::NU;
    constexpr int NV = WinDims<W>::NV;
    constexpr int NRS = 63 + 2 * W;               // staged product rows
    constexpr int LP = 65;                        // uint pitch (4B units)
    for (int e = threadIdx.x; e < NRS * 8; e += 256) {
        const int i = e >> 3, cg = e & 7;
        const int gr = tr0 - W + 1 + i;
        const int c0 = tc0 + cg * 8;
        unsigned int* dst = L + i * LP + cg * 8;
        if (gr < 0 || gr >= IMG) {
#pragma unroll
            for (int j = 0; j < 8; ++j) dst[j] = 0u;
            continue;
        }
        float va[NV], vs[NV];
        loadRowWinH<W>(daz + (long)gr * IMG, c0, va);
        loadRowWin<W>(dsz + (long)gr * IMG, c0, vs);
        float p1[NV], p2[NV];
#pragma unroll
        for (int k = 0; k < NU; ++k) { p1[k] = va[k] * vs[k]; p2[k] = va[k] * va[k]; }
        float s1 = 0.f, s2 = 0.f;
#pragma unroll
        for (int k = A - W + 1; k <= A + W; ++k) { s1 += p1[k]; s2 += p2[k]; }
#pragma unroll
        for (int j = 0; j < 8; ++j) {
            half2v h;
            h[0] = (half_t)s1; h[1] = (half_t)s2;
            dst[j] = __builtin_bit_cast(unsigned int, h);
            if (j < 7) {
                s1 += p1[A + W + 1 + j] - p1[A - W + 1 + j];
                s2 += p2[A + W + 1 + j] - p2[A - W + 1 + j];
            }
        }
    }
}

// w=8: thr = 1 - sab/(sqrt(saa*s_ms)+eps) -> half field. grid (8,8,32).
__global__ __launch_bounds__(256) void kFusedThr(const half_t* __restrict__ daMS,
                                                 const float* __restrict__ daPAN,
                                                 const float* __restrict__ saa,
                                                 half_t* __restrict__ thr) {
    constexpr int W = 8, LP = 65, NRS = 63 + 2 * W;   // 79
    __shared__ unsigned int L[NRS * LP];
    const int z = blockIdx.z, b = z >> 3;
    const int tr0 = blockIdx.y * 64, tc0 = blockIdx.x * 64;
    stageProducts<W>(daMS + (long)z * HWSZ, daPAN + (long)b * HWSZ, tr0, tc0, L);
    __syncthreads();
    const int c = threadIdx.x & 63, q = threadIdx.x >> 6;
    const int ro0 = q * 16;
    float s1 = 0.f, s2 = 0.f;
#pragma unroll
    for (int k = 0; k < 2 * W; ++k) {
        const half2v h = __builtin_bit_cast(half2v, L[(ro0 + k) * LP + c]);
        s1 += (float)h[0]; s2 += (float)h[1];
    }
    const float* sz = saa + (long)b * HWSZ + tc0 + c;
    half_t* tz = thr + (long)z * HWSZ + tc0 + c;
#pragma unroll
    for (int j = 0; j < 16; ++j) {
        const int r = tr0 + ro0 + j;
        const float sa = sz[(long)r * IMG];
        const float den = sqrtf(fmaxf(sa * s2, 0.f)) + 1e-20f;
        tz[(long)r * IMG] = (half_t)(1.0f - s1 / den);
        if (j < 15) {
            const half2v ha = __builtin_bit_cast(half2v, L[(ro0 + j + 2 * W) * LP + c]);
            const half2v hs = __builtin_bit_cast(half2v, L[(ro0 + j) * LP + c]);
            s1 += (float)ha[0] - (float)hs[0];
            s2 += (float)ha[1] - (float)hs[1];
        }
    }
}

// w=2: X = 1 - max(xcorr,-1), Y-reduce vs thr. grid (8,8,32).
__global__ __launch_bounds__(256) void kFusedY(const half_t* __restrict__ daOUT,
                                               const float* __restrict__ dbPAN,
                                               const float* __restrict__ sbb,
                                               const half_t* __restrict__ thr,
                                               double* __restrict__ acc) {
    constexpr int W = 2, LP = 65, NRS = 63 + 2 * W;   // 67
    __shared__ unsigned int L[NRS * LP];
    __shared__ double red[4];
    const int z = blockIdx.z, b = z >> 3;
    const int tr0 = blockIdx.y * 64, tc0 = blockIdx.x * 64;
    stageProducts<W>(daOUT + (long)z * HWSZ, dbPAN + (long)b * HWSZ, tr0, tc0, L);
    __syncthreads();
    const int c = threadIdx.x & 63, q = threadIdx.x >> 6;
    const int ro0 = q * 16;
    float s1 = 0.f, s2 = 0.f;
#pragma unroll
    for (int k = 0; k < 2 * W; ++k) {
        const half2v h = __builtin_bit_cast(half2v, L[(ro0 + k) * LP + c]);
        s1 += (float)h[0]; s2 += (float)h[1];
    }
    const float* sz = sbb + (long)b * HWSZ + tc0 + c;
    const half_t* tz = thr + (long)z * HWSZ + tc0 + c;
    double ysum = 0.0;
#pragma unroll
    for (int j = 0; j < 16; ++j) {
        const int r = tr0 + ro0 + j;
        const float sb = sz[(long)r * IMG];
        const float den = sqrtf(fmaxf(s2 * sb, 0.f)) + 1e-20f;
        const float Xc = s1 / den;
        const float X = 1.0f - fmaxf(Xc, -1.0f);
        if (X > (float)tz[(long)r * IMG]) ysum += (double)X;
        if (j < 15) {
            const half2v ha = __builtin_bit_cast(half2v, L[(ro0 + j + 2 * W) * LP + c]);
            const half2v hs = __builtin_bit_cast(half2v, L[(ro0 + j) * LP + c]);
            s1 += (float)ha[0] - (float)hs[0];
            s2 += (float)ha[1] - (float)hs[1];
        }
    }
    blockReduceAtomicAdd(ysum, acc + 2, red);
}

// ---------------------------------------------------------------------------
// L_spec: strided MTF conv of outputs (rank-1 factored), H then V+reduce.
__global__ __launch_bounds__(256) void k_spec_h(const float* __restrict__ outputs,
                                                const float* __restrict__ mtf,
                                                float* __restrict__ tmpS) {
    __shared__ float vrow[41];
    const int g = blockIdx.x * 256 + threadIdx.x;
    const int q = g & 31, r = (g >> 5) & 511, z = g >> 14;   // z uniform/block
    const int band = z & 7;
    if (threadIdx.x < 41)
        vrow[threadIdx.x] = mtf[band * 1681 + 20 * 41 + threadIdx.x] /
                            sqrtf(mtf[band * 1681 + 20 * 41 + 20]);
    __syncthreads();
    const float* row = outputs + (long)z * HWSZ + (long)r * IMG;
    float v[56];
#pragma unroll
    for (int f = 0; f < 14; ++f) {
        const int cb = 16 * q - 20 + 4 * f;
        if (cb >= 0 && cb + 3 < IMG) {
            const float4 t = *(const float4*)(row + cb);
            v[4 * f + 0] = t.x; v[4 * f + 1] = t.y;
            v[4 * f + 2] = t.z; v[4 * f + 3] = t.w;
        } else {
#pragma unroll
            for (int u = 0; u < 4; ++u) {
                const int cc = cb + u;
                v[4 * f + u] = (cc >= 0 && cc < IMG) ? row[cc] : 0.f;
            }
        }
    }
    float o[4] = {0.f, 0.f, 0.f, 0.f};
#pragma unroll
    for (int j = 0; j < 41; ++j) {
        const float w = vrow[j];
#pragma unroll
        for (int u = 0; u < 4; ++u) o[u] += w * v[2 + 4 * u + j];
    }
    float* dst = tmpS + ((long)z * IMG + r) * 128 + 4 * q;
    *(float4*)dst = make_float4(o[0], o[1], o[2], o[3]);
}

__global__ __launch_bounds__(256) void k_spec_v(const float* __restrict__ tmpS,
                                                const float* __restrict__ labels,
                                                const float* __restrict__ spec,
                                                const float* __restrict__ mtf,
                                                double* __restrict__ acc) {
    __shared__ double redT[4];
    __shared__ double redM[4];
    __shared__ float ucol[41];
    const int g = blockIdx.x * 256 + threadIdx.x;
    const int q = g & 31, rs = (g >> 5) & 127, z = g >> 12;   // z uniform/block
    const int b = z >> 3, band = z & 7;
    if (threadIdx.x < 41)
        ucol[threadIdx.x] = mtf[band * 1681 + threadIdx.x * 41 + 20] /
                            sqrtf(mtf[band * 1681 + 20 * 41 + 20]);
    __syncthreads();
    const float* base = tmpS + (long)z * IMG * 128 + 4 * q;
    const int rbase = 4 * rs - 18;
    float o[4] = {0.f, 0.f, 0.f, 0.f};
    if (rbase >= 0 && rbase + 40 < IMG) {
#pragma unroll
        for (int i = 0; i < 41; ++i) {
            const float4 v = *(const float4*)(base + (long)(rbase + i) * 128);
            const float w = ucol[i];
            o[0] += w * v.x; o[1] += w * v.y; o[2] += w * v.z; o[3] += w * v.w;
        }
    } else {
        for (int i = 0; i < 41; ++i) {
            const int r = rbase + i;
            if (r >= 0 && r < IMG) {
                const float4 v = *(const float4*)(base + (long)r * 128);
                const float w = ucol[i];
                o[0] += w * v.x; o[1] += w * v.y; o[2] += w * v.z; o[3] += w * v.w;
            }
        }
    }
    const int gr = 2 + 4 * rs;
    float tsum = 0.f, msum = 0.f;
#pragma unroll
    for (int u = 0; u < 4; ++u) {
        const int gc = 2 + 4 * (4 * q + u);
        const float m = spec[(long)band * HWSZ + (long)gr * IMG + gc];
        const float y = labels[((long)b * 9 + band) * HWSZ + (long)gr * IMG + gc];
        tsum += fabsf(o[u] * m - y * m);
        msum += m;
    }
    blockReduceAtomicAdd((double)tsum, acc + 0, redT);
    blockReduceAtomicAdd((double)msum, acc + 1, redM);
}

__global__ void k_final(const double* __restrict__ acc, float* __restrict__ out) {
    double lspec = acc[0] / acc[1];
    double lstruct = acc[2] / (double)(NBATCH * NBANDS * HWSZ);
    out[0] = (float)(lspec + 0.25 * lstruct);
}

// ---------------------------------------------------------------------------
extern "C" void kernel_launch(void* const* d_in, const int* in_sizes, int n_in,
                              void* d_out, int out_size, void* d_ws, size_t ws_size,
                              hipStream_t stream) {
    const float* outputs = (const float*)d_in[0];   // (4,8,512,512)
    const float* labels  = (const float*)d_in[1];   // (4,9,512,512)
    const float* inp     = (const float*)d_in[2];   // (4,9,512,512)
    const float* mtf     = (const float*)d_in[3];   // (8,1,41,41)
    const float* spec    = (const float*)d_in[4];   // (1,8,512,512)
    float* out = (float*)d_out;

    const long IMGB = (long)HWSZ;     // one image in elements
    char* ws = (char*)d_ws;
    double* acc    = (double*)ws;                    // 4 doubles
    float* panf    = (float*)(ws + 1024);            // 4 imgs fp32
    float* tmpH    = panf   + NBATCH * IMGB;         // 4 imgs
    float* da_pan8 = tmpH   + NBATCH * IMGB;         // 4 imgs
    float* saa8    = da_pan8 + NBATCH * IMGB;        // 4 imgs
    float* db_pan2 = saa8   + NBATCH * IMGB;         // 4 imgs
    float* sbb2    = db_pan2 + NBATCH * IMGB;        // 4 imgs
    float* tmpS    = sbb2   + NBATCH * IMGB;         // 8 imgs fp32
    half_t* hT     = (half_t*)(tmpS + 8 * IMGB);     // 32 imgs half (scratch)
    half_t* hDA8   = hT   + 32 * IMGB;               // 32 imgs half: da_ms  (w=8)
    half_t* hDA2   = hDA8 + 32 * IMGB;               // 32 imgs half: da_out (w=2)
    half_t* thrH   = hDA2 + 32 * IMGB;               // 32 imgs half: thr field

    hipMemsetAsync(acc, 0, 4 * sizeof(double), stream);

    // --- per-batch shared fields (fp32) ----------------------------------
    k_pan_h<<<dim3(2, 512, NBATCH), 256, 0, stream>>>(inp, mtf, tmpH);
    k_pan_v<<<dim3(2, 512, NBATCH), 256, 0, stream>>>(tmpH, mtf, panf);
    k_da<8><<<dim3(16, 16, NBATCH), 256, 0, stream>>>(panf, (long)HWSZ, da_pan8);
    k_sq<8><<<dim3(16, 16, NBATCH), 256, 0, stream>>>(da_pan8, saa8);
    k_da<2><<<dim3(16, 16, NBATCH), 256, 0, stream>>>(labels + 8 * IMGB,
                                                      (long)9 * HWSZ, db_pan2);
    k_sq<2><<<dim3(16, 16, NBATCH), 256, 0, stream>>>(db_pan2, sbb2);

    // --- L_spec ----------------------------------------------------------
    k_spec_h<<<2048, 256, 0, stream>>>(outputs, mtf, tmpS);
    k_spec_v<<<512, 256, 0, stream>>>(tmpS, labels, spec, mtf, acc);

    // --- da fields for both xcorr widths ---------------------------------
    kHbox<8><<<4096, 256, 0, stream>>>(inp, 9 * IMGB, IMGB, hT);
    kVda<8><<<1024, 256, 0, stream>>>(hT, inp, 9 * IMGB, IMGB, hDA8);   // da_ms
    kHbox<2><<<4096, 256, 0, stream>>>(outputs, 8 * IMGB, IMGB, hT);
    kVda<2><<<1024, 256, 0, stream>>>(hT, outputs, 8 * IMGB, IMGB, hDA2); // da_out

    // --- fused product+box pipelines -------------------------------------
    kFusedThr<<<dim3(8, 8, 32), 256, 0, stream>>>(hDA8, da_pan8, saa8, thrH);
    kFusedY<<<dim3(8, 8, 32), 256, 0, stream>>>(hDA2, db_pan2, sbb2, thrH, acc);

    k_final<<<1, 1, 0, stream>>>(acc, out);
}

// Round 4
// 304.146 us; speedup vs baseline: 1.1869x; 1.0284x over previous
//
#include <hip/hip_runtime.h>
#include <hip/hip_bf16.h>

// Problem constants
#define HWSZ   262144   // 512*512
#define IMG    512
#define NBATCH 4
#define NBANDS 8

typedef _Float16 half_t;
typedef _Float16 half2v __attribute__((ext_vector_type(2)));
typedef _Float16 half4v __attribute__((ext_vector_type(4)));
typedef _Float16 half8v __attribute__((ext_vector_type(8)));

// ---------------------------------------------------------------------------
// Block-level reduction: wave shuffle + LDS + one double atomic per block.
__device__ __forceinline__ void blockReduceAtomicAdd(double v, double* target,
                                                     double* red) {
    for (int off = 32; off > 0; off >>= 1) v += __shfl_down(v, off, 64);
    const int wave = threadIdx.x >> 6, lane = threadIdx.x & 63;
    if (lane == 0) red[wave] = v;
    __syncthreads();
    if (threadIdx.x == 0) atomicAdd(target, red[0] + red[1] + red[2] + red[3]);
}

// ---------------------------------------------------------------------------
// Pan smoothing (edge-pad 41x41 Gaussian, rank-1 factored), horizontal pass.
__global__ __launch_bounds__(256) void k_pan_h(const float* __restrict__ inp,
                                               const float* __restrict__ mtf,
                                               float* __restrict__ tmpH) {
    __shared__ float seg[296];
    __shared__ float vrow[41];
    const int tid = threadIdx.x;
    const int b = blockIdx.z, r = blockIdx.y, c0 = blockIdx.x * 256;
    if (tid < 41) vrow[tid] = mtf[20 * 41 + tid] / sqrtf(mtf[20 * 41 + 20]);
    const float* pan = inp + ((long)b * 9 + 8) * HWSZ + (long)r * IMG;
    for (int e = tid; e < 296; e += 256) {
        int c = c0 - 20 + e;
        c = min(max(c, 0), IMG - 1);
        seg[e] = pan[c];
    }
    __syncthreads();
    float s = 0.f;
#pragma unroll
    for (int j = 0; j < 41; ++j) s += vrow[j] * seg[tid + j];
    tmpH[(long)b * HWSZ + (long)r * IMG + c0 + tid] = s;
}

__global__ __launch_bounds__(256) void k_pan_v(const float* __restrict__ tmpH,
                                               const float* __restrict__ mtf,
                                               float* __restrict__ panf) {
    __shared__ float ucol[41];
    const int tid = threadIdx.x;
    const int b = blockIdx.z, r = blockIdx.y, c = blockIdx.x * 256 + tid;
    if (tid < 41) ucol[tid] = mtf[tid * 41 + 20] / sqrtf(mtf[20 * 41 + 20]);
    __syncthreads();
    const float* base = tmpH + (long)b * HWSZ;
    float s = 0.f;
#pragma unroll
    for (int i = 0; i < 41; ++i) {
        int rr = min(max(r - 20 + i, 0), IMG - 1);
        s += ucol[i] * base[(long)rr * IMG + c];
    }
    panf[(long)b * HWSZ + (long)r * IMG + c] = s;
}

// ---------------------------------------------------------------------------
// Small-field (4-image) helpers, LDS tile based (cheap at this size).
template <int W>
__global__ __launch_bounds__(256) void k_da(const float* __restrict__ in,
                                            long inBatchStride,
                                            float* __restrict__ out) {
    constexpr int TS = 32, WIN = 2 * W, NN = 4 * W * W, RE = TS + WIN - 1;
    constexpr int SR = RE;
    constexpr int ST = 33;
    __shared__ float RAW[RE * SR];
    __shared__ float T[RE * ST];
    const int tid = threadIdx.x;
    const int tr0 = blockIdx.y * TS, tc0 = blockIdx.x * TS;
    const float* src = in + (long)blockIdx.z * inBatchStride;
    for (int e = tid; e < RE * RE; e += 256) {
        int r = e / RE, c = e % RE;
        int gr = tr0 - (W - 1) + r, gc = tc0 - (W - 1) + c;
        float v = 0.f;
        if (gr >= 0 && gr < IMG && gc >= 0 && gc < IMG) v = src[(long)gr * IMG + gc];
        RAW[r * SR + c] = v;
    }
    __syncthreads();
    for (int e = tid; e < RE * TS; e += 256) {
        int r = e >> 5, j = e & 31;
        float s = 0.f;
#pragma unroll
        for (int k = 0; k < WIN; ++k) s += RAW[r * SR + j + k];
        T[r * ST + j] = s;
    }
    __syncthreads();
    float* dst = out + (long)blockIdx.z * HWSZ;
    for (int e = tid; e < TS * TS; e += 256) {
        int pr = e >> 5, pc = e & 31;
        float s = 0.f;
#pragma unroll
        for (int k = 0; k < WIN; ++k) s += T[(pr + k) * ST + pc];
        float da = RAW[(pr + W - 1) * SR + (pc + W - 1)] - s * (1.0f / NN);
        dst[(long)(tr0 + pr) * IMG + tc0 + pc] = da;
    }
}

template <int W>
__global__ __launch_bounds__(256) void k_sq(const float* __restrict__ in,
                                            float* __restrict__ out) {
    constexpr int TS = 32, WIN = 2 * W, RE = TS + WIN - 1;
    constexpr int SR = RE, ST = 33;
    __shared__ float RAW[RE * SR];
    __shared__ float T[RE * ST];
    const int tid = threadIdx.x;
    const int tr0 = blockIdx.y * TS, tc0 = blockIdx.x * TS;
    const float* src = in + (long)blockIdx.z * HWSZ;
    for (int e = tid; e < RE * RE; e += 256) {
        int r = e / RE, c = e % RE;
        int gr = tr0 - (W - 1) + r, gc = tc0 - (W - 1) + c;
        float v = 0.f;
        if (gr >= 0 && gr < IMG && gc >= 0 && gc < IMG) v = src[(long)gr * IMG + gc];
        RAW[r * SR + c] = v;
    }
    __syncthreads();
    for (int e = tid; e < RE * TS; e += 256) {
        int r = e >> 5, j = e & 31;
        float s = 0.f;
#pragma unroll
        for (int k = 0; k < WIN; ++k) {
            float v = RAW[r * SR + j + k];
            s += v * v;
        }
        T[r * ST + j] = s;
    }
    __syncthreads();
    float* dst = out + (long)blockIdx.z * HWSZ;
    for (int e = tid; e < TS * TS; e += 256) {
        int pr = e >> 5, pc = e & 31;
        float s = 0.f;
#pragma unroll
        for (int k = 0; k < WIN; ++k) s += T[(pr + k) * ST + pc];
        dst[(long)(tr0 + pr) * IMG + tc0 + pc] = s;
    }
}

// ---------------------------------------------------------------------------
// Sliding-window helpers for the full-size (32-image) path.

template <int W> struct WinDims {
    static constexpr int A  = (W + 3) & ~3;
    static constexpr int NU = A + W + 8;              // elements actually used
    static constexpr int NF = (NU + 3) / 4;           // 4-elem chunks loaded
    static constexpr int NV = NF * 4;                 // padded array size
};

template <int W>
__device__ __forceinline__ void loadRowWin(const float* __restrict__ row, int c0,
                                           float* v) {
    constexpr int A = WinDims<W>::A;
    constexpr int NF = WinDims<W>::NF;
#pragma unroll
    for (int f = 0; f < NF; ++f) {
        const int cb = c0 - A + 4 * f;
        if (cb >= 0 && cb + 3 < IMG) {
            const float4 t = *(const float4*)(row + cb);
            v[4 * f + 0] = t.x; v[4 * f + 1] = t.y;
            v[4 * f + 2] = t.z; v[4 * f + 3] = t.w;
        } else {
#pragma unroll
            for (int u = 0; u < 4; ++u) {
                const int c = cb + u;
                v[4 * f + u] = (c >= 0 && c < IMG) ? row[c] : 0.f;
            }
        }
    }
}

template <int W>
__device__ __forceinline__ void loadRowWinH(const half_t* __restrict__ row, int c0,
                                            float* v) {
    constexpr int A = WinDims<W>::A;
    constexpr int NF = WinDims<W>::NF;
#pragma unroll
    for (int f = 0; f < NF; ++f) {
        const int cb = c0 - A + 4 * f;   // multiple of 4 -> 8B aligned
        if (cb >= 0 && cb + 3 < IMG) {
            const half4v t = *(const half4v*)(row + cb);
            v[4 * f + 0] = (float)t[0]; v[4 * f + 1] = (float)t[1];
            v[4 * f + 2] = (float)t[2]; v[4 * f + 3] = (float)t[3];
        } else {
#pragma unroll
            for (int u = 0; u < 4; ++u) {
                const int c = cb + u;
                v[4 * f + u] = (c >= 0 && c < IMG) ? (float)row[c] : 0.f;
            }
        }
    }
}

// ---------------------------------------------------------------------------
// Fused da kernel (replaces kHbox + kVda): per 64x64 tile, H-box raw rows
// into fp32 LDS (per-thread sliding window), one sync, V-box by register
// sliding down columns + epilogue da = orig - box/n (half out). The orig
// re-read in phase 2 hits L1/L2 (phase 1 just fetched those lines).
// LDS pitch 65: both store and gather patterns are 2-way max (free).
// grid (8,8,32) x 256.
template <int W>
__global__ __launch_bounds__(256) void kDAtile(const float* __restrict__ in,
                                               long sB, long sC,
                                               half_t* __restrict__ out) {
    constexpr int A = WinDims<W>::A;
    constexpr int NV = WinDims<W>::NV;
    constexpr int NRS = 63 + 2 * W;               // staged t rows
    constexpr int LP = 65;                        // float pitch
    constexpr int NN = 4 * W * W;
    __shared__ float T[NRS * LP];
    const int z = blockIdx.z;
    const int tr0 = blockIdx.y * 64, tc0 = blockIdx.x * 64;
    const float* img = in + (long)(z >> 3) * sB + (long)(z & 7) * sC;

    // phase 1: t = H-box(raw), rows tr0-W+1 .. tr0+62+W, cols tc0..tc0+63
    for (int e = threadIdx.x; e < NRS * 8; e += 256) {
        const int i = e >> 3, cg = e & 7;
        const int gr = tr0 - W + 1 + i;
        float* dst = &T[i * LP + cg * 8];
        if (gr < 0 || gr >= IMG) {
#pragma unroll
            for (int j = 0; j < 8; ++j) dst[j] = 0.f;
            continue;
        }
        float v[NV];
        loadRowWin<W>(img + (long)gr * IMG, tc0 + cg * 8, v);
        float s = 0.f;
#pragma unroll
        for (int k = A - W + 1; k <= A + W; ++k) s += v[k];
        dst[0] = s;
#pragma unroll
        for (int j = 1; j < 8; ++j) {
            s += v[A + W + j] - v[A - W + j];
            dst[j] = s;
        }
    }
    __syncthreads();

    // phase 2: V-slide + epilogue
    const int c = threadIdx.x & 63, q = threadIdx.x >> 6;
    const int ro0 = q * 16;
    float s = 0.f;
#pragma unroll
    for (int k = 0; k < 2 * W; ++k) s += T[(ro0 + k) * LP + c];
    const float* oz = img + tc0 + c;
    half_t* dz = out + (long)z * HWSZ + tc0 + c;
#pragma unroll
    for (int j = 0; j < 16; ++j) {
        const int r = tr0 + ro0 + j;
        const float o = oz[(long)r * IMG];
        dz[(long)r * IMG] = (half_t)(o - s * (1.0f / NN));
        if (j < 15) s += T[(ro0 + j + 2 * W) * LP + c] - T[(ro0 + j) * LP + c];
    }
}

// ---------------------------------------------------------------------------
// Fused product + H-box staging (verified in round 3): per 64x64 tile, H-box
// of (da*dshared, da*da) rows into LDS as packed half2(p1,p2).
template <int W>
__device__ __forceinline__ void stageProducts(const half_t* __restrict__ daz,
                                              const float* __restrict__ dsz,
                                              int tr0, int tc0,
                                              unsigned int* L) {
    constexpr int A = WinDims<W>::A;
    constexpr int NU = WinDims<W>::NU;
    constexpr int NV = WinDims<W>::NV;
    constexpr int NRS = 63 + 2 * W;               // staged product rows
    constexpr int LP = 65;                        // uint pitch (4B units)
    for (int e = threadIdx.x; e < NRS * 8; e += 256) {
        const int i = e >> 3, cg = e & 7;
        const int gr = tr0 - W + 1 + i;
        const int c0 = tc0 + cg * 8;
        unsigned int* dst = L + i * LP + cg * 8;
        if (gr < 0 || gr >= IMG) {
#pragma unroll
            for (int j = 0; j < 8; ++j) dst[j] = 0u;
            continue;
        }
        float va[NV], vs[NV];
        loadRowWinH<W>(daz + (long)gr * IMG, c0, va);
        loadRowWin<W>(dsz + (long)gr * IMG, c0, vs);
        float p1[NV], p2[NV];
#pragma unroll
        for (int k = 0; k < NU; ++k) { p1[k] = va[k] * vs[k]; p2[k] = va[k] * va[k]; }
        float s1 = 0.f, s2 = 0.f;
#pragma unroll
        for (int k = A - W + 1; k <= A + W; ++k) { s1 += p1[k]; s2 += p2[k]; }
#pragma unroll
        for (int j = 0; j < 8; ++j) {
            half2v h;
            h[0] = (half_t)s1; h[1] = (half_t)s2;
            dst[j] = __builtin_bit_cast(unsigned int, h);
            if (j < 7) {
                s1 += p1[A + W + 1 + j] - p1[A - W + 1 + j];
                s2 += p2[A + W + 1 + j] - p2[A - W + 1 + j];
            }
        }
    }
}

// ---------------------------------------------------------------------------
// Fully fused structural kernel: w=8 phase -> thr in REGISTERS (no thr
// field round-trip), then w=2 phase -> X vs thr, Y-reduce. Thread mapping
// identical in both V-phases so thrv[16] stays in registers. grid (8,8,32).
__global__ __launch_bounds__(256) void kFusedXY(const half_t* __restrict__ daMS,
                                                const float* __restrict__ daPAN,
                                                const float* __restrict__ saa,
                                                const half_t* __restrict__ daOUT,
                                                const float* __restrict__ dbPAN,
                                                const float* __restrict__ sbb,
                                                double* __restrict__ acc) {
    constexpr int LP = 65;
    constexpr int NRS8 = 63 + 16;                 // 79 (w=8)
    __shared__ unsigned int L[NRS8 * LP];
    __shared__ double red[4];
    const int z = blockIdx.z, b = z >> 3;
    const int tr0 = blockIdx.y * 64, tc0 = blockIdx.x * 64;
    const int c = threadIdx.x & 63, q = threadIdx.x >> 6;
    const int ro0 = q * 16;

    float thrv[16];
    {   // ---------------- w = 8: thr ----------------
        constexpr int W = 8;
        stageProducts<W>(daMS + (long)z * HWSZ, daPAN + (long)b * HWSZ,
                         tr0, tc0, L);
        __syncthreads();
        float s1 = 0.f, s2 = 0.f;
#pragma unroll
        for (int k = 0; k < 2 * W; ++k) {
            const half2v h = __builtin_bit_cast(half2v, L[(ro0 + k) * LP + c]);
            s1 += (float)h[0]; s2 += (float)h[1];
        }
        const float* sz = saa + (long)b * HWSZ + tc0 + c;
#pragma unroll
        for (int j = 0; j < 16; ++j) {
            const int r = tr0 + ro0 + j;
            const float sa = sz[(long)r * IMG];
            const float den = sqrtf(fmaxf(sa * s2, 0.f)) + 1e-20f;
            thrv[j] = 1.0f - s1 / den;
            if (j < 15) {
                const half2v ha = __builtin_bit_cast(half2v, L[(ro0 + j + 2 * W) * LP + c]);
                const half2v hs = __builtin_bit_cast(half2v, L[(ro0 + j) * LP + c]);
                s1 += (float)ha[0] - (float)hs[0];
                s2 += (float)ha[1] - (float)hs[1];
            }
        }
        __syncthreads();   // L dead; safe to restage
    }
    double ysum = 0.0;
    {   // ---------------- w = 2: X vs thr, Y ----------------
        constexpr int W = 2;
        stageProducts<W>(daOUT + (long)z * HWSZ, dbPAN + (long)b * HWSZ,
                         tr0, tc0, L);
        __syncthreads();
        float s1 = 0.f, s2 = 0.f;
#pragma unroll
        for (int k = 0; k < 2 * W; ++k) {
            const half2v h = __builtin_bit_cast(half2v, L[(ro0 + k) * LP + c]);
            s1 += (float)h[0]; s2 += (float)h[1];
        }
        const float* sz = sbb + (long)b * HWSZ + tc0 + c;
#pragma unroll
        for (int j = 0; j < 16; ++j) {
            const float sb = sz[(long)(tr0 + ro0 + j) * IMG];
            const float den = sqrtf(fmaxf(s2 * sb, 0.f)) + 1e-20f;
            const float Xc = s1 / den;
            const float X = 1.0f - fmaxf(Xc, -1.0f);
            if (X > thrv[j]) ysum += (double)X;
            if (j < 15) {
                const half2v ha = __builtin_bit_cast(half2v, L[(ro0 + j + 2 * W) * LP + c]);
                const half2v hs = __builtin_bit_cast(half2v, L[(ro0 + j) * LP + c]);
                s1 += (float)ha[0] - (float)hs[0];
                s2 += (float)ha[1] - (float)hs[1];
            }
        }
    }
    blockReduceAtomicAdd(ysum, acc + 2, red);
}

// ---------------------------------------------------------------------------
// L_spec: strided MTF conv of outputs (rank-1 factored), H then V+reduce.
__global__ __launch_bounds__(256) void k_spec_h(const float* __restrict__ outputs,
                                                const float* __restrict__ mtf,
                                                float* __restrict__ tmpS) {
    __shared__ float vrow[41];
    const int g = blockIdx.x * 256 + threadIdx.x;
    const int q = g & 31, r = (g >> 5) & 511, z = g >> 14;   // z uniform/block
    const int band = z & 7;
    if (threadIdx.x < 41)
        vrow[threadIdx.x] = mtf[band * 1681 + 20 * 41 + threadIdx.x] /
                            sqrtf(mtf[band * 1681 + 20 * 41 + 20]);
    __syncthreads();
    const float* row = outputs + (long)z * HWSZ + (long)r * IMG;
    float v[56];
#pragma unroll
    for (int f = 0; f < 14; ++f) {
        const int cb = 16 * q - 20 + 4 * f;
        if (cb >= 0 && cb + 3 < IMG) {
            const float4 t = *(const float4*)(row + cb);
            v[4 * f + 0] = t.x; v[4 * f + 1] = t.y;
            v[4 * f + 2] = t.z; v[4 * f + 3] = t.w;
        } else {
#pragma unroll
            for (int u = 0; u < 4; ++u) {
                const int cc = cb + u;
                v[4 * f + u] = (cc >= 0 && cc < IMG) ? row[cc] : 0.f;
            }
        }
    }
    float o[4] = {0.f, 0.f, 0.f, 0.f};
#pragma unroll
    for (int j = 0; j < 41; ++j) {
        const float w = vrow[j];
#pragma unroll
        for (int u = 0; u < 4; ++u) o[u] += w * v[2 + 4 * u + j];
    }
    float* dst = tmpS + ((long)z * IMG + r) * 128 + 4 * q;
    *(float4*)dst = make_float4(o[0], o[1], o[2], o[3]);
}

__global__ __launch_bounds__(256) void k_spec_v(const float* __restrict__ tmpS,
                                                const float* __restrict__ labels,
                                                const float* __restrict__ spec,
                                                const float* __restrict__ mtf,
                                                double* __restrict__ acc) {
    __shared__ double redT[4];
    __shared__ double redM[4];
    __shared__ float ucol[41];
    const int g = blockIdx.x * 256 + threadIdx.x;
    const int q = g & 31, rs = (g >> 5) & 127, z = g >> 12;   // z uniform/block
    const int b = z >> 3, band = z & 7;
    if (threadIdx.x < 41)
        ucol[threadIdx.x] = mtf[band * 1681 + threadIdx.x * 41 + 20] /
                            sqrtf(mtf[band * 1681 + 20 * 41 + 20]);
    __syncthreads();
    const float* base = tmpS + (long)z * IMG * 128 + 4 * q;
    const int rbase = 4 * rs - 18;
    float o[4] = {0.f, 0.f, 0.f, 0.f};
    if (rbase >= 0 && rbase + 40 < IMG) {
#pragma unroll
        for (int i = 0; i < 41; ++i) {
            const float4 v = *(const float4*)(base + (long)(rbase + i) * 128);
            const float w = ucol[i];
            o[0] += w * v.x; o[1] += w * v.y; o[2] += w * v.z; o[3] += w * v.w;
        }
    } else {
        for (int i = 0; i < 41; ++i) {
            const int r = rbase + i;
            if (r >= 0 && r < IMG) {
                const float4 v = *(const float4*)(base + (long)r * 128);
                const float w = ucol[i];
                o[0] += w * v.x; o[1] += w * v.y; o[2] += w * v.z; o[3] += w * v.w;
            }
        }
    }
    const int gr = 2 + 4 * rs;
    float tsum = 0.f, msum = 0.f;
#pragma unroll
    for (int u = 0; u < 4; ++u) {
        const int gc = 2 + 4 * (4 * q + u);
        const float m = spec[(long)band * HWSZ + (long)gr * IMG + gc];
        const float y = labels[((long)b * 9 + band) * HWSZ + (long)gr * IMG + gc];
        tsum += fabsf(o[u] * m - y * m);
        msum += m;
    }
    blockReduceAtomicAdd((double)tsum, acc + 0, redT);
    blockReduceAtomicAdd((double)msum, acc + 1, redM);
}

__global__ void k_final(const double* __restrict__ acc, float* __restrict__ out) {
    double lspec = acc[0] / acc[1];
    double lstruct = acc[2] / (double)(NBATCH * NBANDS * HWSZ);
    out[0] = (float)(lspec + 0.25 * lstruct);
}

// ---------------------------------------------------------------------------
extern "C" void kernel_launch(void* const* d_in, const int* in_sizes, int n_in,
                              void* d_out, int out_size, void* d_ws, size_t ws_size,
                              hipStream_t stream) {
    const float* outputs = (const float*)d_in[0];   // (4,8,512,512)
    const float* labels  = (const float*)d_in[1];   // (4,9,512,512)
    const float* inp     = (const float*)d_in[2];   // (4,9,512,512)
    const float* mtf     = (const float*)d_in[3];   // (8,1,41,41)
    const float* spec    = (const float*)d_in[4];   // (1,8,512,512)
    float* out = (float*)d_out;

    const long IMGB = (long)HWSZ;     // one image in elements
    char* ws = (char*)d_ws;
    double* acc    = (double*)ws;                    // 4 doubles
    float* panf    = (float*)(ws + 1024);            // 4 imgs fp32
    float* tmpH    = panf   + NBATCH * IMGB;         // 4 imgs
    float* da_pan8 = tmpH   + NBATCH * IMGB;         // 4 imgs
    float* saa8    = da_pan8 + NBATCH * IMGB;        // 4 imgs
    float* db_pan2 = saa8   + NBATCH * IMGB;         // 4 imgs
    float* sbb2    = db_pan2 + NBATCH * IMGB;        // 4 imgs
    float* tmpS    = sbb2   + NBATCH * IMGB;         // 8 imgs fp32
    half_t* hDA8   = (half_t*)(tmpS + 8 * IMGB);     // 32 imgs half: da_ms  (w=8)
    half_t* hDA2   = hDA8 + 32 * IMGB;               // 32 imgs half: da_out (w=2)

    hipMemsetAsync(acc, 0, 4 * sizeof(double), stream);

    // --- per-batch shared fields (fp32) ----------------------------------
    k_pan_h<<<dim3(2, 512, NBATCH), 256, 0, stream>>>(inp, mtf, tmpH);
    k_pan_v<<<dim3(2, 512, NBATCH), 256, 0, stream>>>(tmpH, mtf, panf);
    k_da<8><<<dim3(16, 16, NBATCH), 256, 0, stream>>>(panf, (long)HWSZ, da_pan8);
    k_sq<8><<<dim3(16, 16, NBATCH), 256, 0, stream>>>(da_pan8, saa8);
    k_da<2><<<dim3(16, 16, NBATCH), 256, 0, stream>>>(labels + 8 * IMGB,
                                                      (long)9 * HWSZ, db_pan2);
    k_sq<2><<<dim3(16, 16, NBATCH), 256, 0, stream>>>(db_pan2, sbb2);

    // --- L_spec ----------------------------------------------------------
    k_spec_h<<<2048, 256, 0, stream>>>(outputs, mtf, tmpS);
    k_spec_v<<<512, 256, 0, stream>>>(tmpS, labels, spec, mtf, acc);

    // --- da fields for both xcorr widths (fused H+V box) -----------------
    kDAtile<8><<<dim3(8, 8, 32), 256, 0, stream>>>(inp, 9 * IMGB, IMGB, hDA8);
    kDAtile<2><<<dim3(8, 8, 32), 256, 0, stream>>>(outputs, 8 * IMGB, IMGB, hDA2);

    // --- fused products + box + thr + X + Y reduce ------------------------
    kFusedXY<<<dim3(8, 8, 32), 256, 0, stream>>>(hDA8, da_pan8, saa8,
                                                 hDA2, db_pan2, sbb2, acc);

    k_final<<<1, 1, 0, stream>>>(acc, out);
}

// Round 5
// 281.292 us; speedup vs baseline: 1.2834x; 1.0812x over previous
//
#include <hip/hip_runtime.h>
#include <hip/hip_bf16.h>

// Problem constants
#define HWSZ   262144   // 512*512
#define IMG    512
#define NBATCH 4
#define NBANDS 8

typedef _Float16 half_t;
typedef _Float16 half2v __attribute__((ext_vector_type(2)));
typedef _Float16 half4v __attribute__((ext_vector_type(4)));
typedef _Float16 half8v __attribute__((ext_vector_type(8)));

// ---------------------------------------------------------------------------
// Block-level reduction: wave shuffle + LDS + one double atomic per block.
__device__ __forceinline__ void blockReduceAtomicAdd(double v, double* target,
                                                     double* red) {
    for (int off = 32; off > 0; off >>= 1) v += __shfl_down(v, off, 64);
    const int wave = threadIdx.x >> 6, lane = threadIdx.x & 63;
    if (lane == 0) red[wave] = v;
    __syncthreads();
    if (threadIdx.x == 0) atomicAdd(target, red[0] + red[1] + red[2] + red[3]);
}

// ---------------------------------------------------------------------------
// Pan smoothing (edge-pad 41x41 Gaussian, rank-1 factored), horizontal pass.
__global__ __launch_bounds__(256) void k_pan_h(const float* __restrict__ inp,
                                               const float* __restrict__ mtf,
                                               float* __restrict__ tmpH) {
    __shared__ float seg[296];
    __shared__ float vrow[41];
    const int tid = threadIdx.x;
    const int b = blockIdx.z, r = blockIdx.y, c0 = blockIdx.x * 256;
    if (tid < 41) vrow[tid] = mtf[20 * 41 + tid] / sqrtf(mtf[20 * 41 + 20]);
    const float* pan = inp + ((long)b * 9 + 8) * HWSZ + (long)r * IMG;
    for (int e = tid; e < 296; e += 256) {
        int c = c0 - 20 + e;
        c = min(max(c, 0), IMG - 1);
        seg[e] = pan[c];
    }
    __syncthreads();
    float s = 0.f;
#pragma unroll
    for (int j = 0; j < 41; ++j) s += vrow[j] * seg[tid + j];
    tmpH[(long)b * HWSZ + (long)r * IMG + c0 + tid] = s;
}

__global__ __launch_bounds__(256) void k_pan_v(const float* __restrict__ tmpH,
                                               const float* __restrict__ mtf,
                                               float* __restrict__ panf) {
    __shared__ float ucol[41];
    const int tid = threadIdx.x;
    const int b = blockIdx.z, r = blockIdx.y, c = blockIdx.x * 256 + tid;
    if (tid < 41) ucol[tid] = mtf[tid * 41 + 20] / sqrtf(mtf[20 * 41 + 20]);
    __syncthreads();
    const float* base = tmpH + (long)b * HWSZ;
    float s = 0.f;
#pragma unroll
    for (int i = 0; i < 41; ++i) {
        int rr = min(max(r - 20 + i, 0), IMG - 1);
        s += ucol[i] * base[(long)rr * IMG + c];
    }
    panf[(long)b * HWSZ + (long)r * IMG + c] = s;
}

// ---------------------------------------------------------------------------
// Small-field (4-image) helpers, LDS tile based (cheap at this size).
template <int W>
__global__ __launch_bounds__(256) void k_da(const float* __restrict__ in,
                                            long inBatchStride,
                                            float* __restrict__ out) {
    constexpr int TS = 32, WIN = 2 * W, NN = 4 * W * W, RE = TS + WIN - 1;
    constexpr int SR = RE;
    constexpr int ST = 33;
    __shared__ float RAW[RE * SR];
    __shared__ float T[RE * ST];
    const int tid = threadIdx.x;
    const int tr0 = blockIdx.y * TS, tc0 = blockIdx.x * TS;
    const float* src = in + (long)blockIdx.z * inBatchStride;
    for (int e = tid; e < RE * RE; e += 256) {
        int r = e / RE, c = e % RE;
        int gr = tr0 - (W - 1) + r, gc = tc0 - (W - 1) + c;
        float v = 0.f;
        if (gr >= 0 && gr < IMG && gc >= 0 && gc < IMG) v = src[(long)gr * IMG + gc];
        RAW[r * SR + c] = v;
    }
    __syncthreads();
    for (int e = tid; e < RE * TS; e += 256) {
        int r = e >> 5, j = e & 31;
        float s = 0.f;
#pragma unroll
        for (int k = 0; k < WIN; ++k) s += RAW[r * SR + j + k];
        T[r * ST + j] = s;
    }
    __syncthreads();
    float* dst = out + (long)blockIdx.z * HWSZ;
    for (int e = tid; e < TS * TS; e += 256) {
        int pr = e >> 5, pc = e & 31;
        float s = 0.f;
#pragma unroll
        for (int k = 0; k < WIN; ++k) s += T[(pr + k) * ST + pc];
        float da = RAW[(pr + W - 1) * SR + (pc + W - 1)] - s * (1.0f / NN);
        dst[(long)(tr0 + pr) * IMG + tc0 + pc] = da;
    }
}

template <int W>
__global__ __launch_bounds__(256) void k_sq(const float* __restrict__ in,
                                            float* __restrict__ out) {
    constexpr int TS = 32, WIN = 2 * W, RE = TS + WIN - 1;
    constexpr int SR = RE, ST = 33;
    __shared__ float RAW[RE * SR];
    __shared__ float T[RE * ST];
    const int tid = threadIdx.x;
    const int tr0 = blockIdx.y * TS, tc0 = blockIdx.x * TS;
    const float* src = in + (long)blockIdx.z * HWSZ;
    for (int e = tid; e < RE * RE; e += 256) {
        int r = e / RE, c = e % RE;
        int gr = tr0 - (W - 1) + r, gc = tc0 - (W - 1) + c;
        float v = 0.f;
        if (gr >= 0 && gr < IMG && gc >= 0 && gc < IMG) v = src[(long)gr * IMG + gc];
        RAW[r * SR + c] = v;
    }
    __syncthreads();
    for (int e = tid; e < RE * TS; e += 256) {
        int r = e >> 5, j = e & 31;
        float s = 0.f;
#pragma unroll
        for (int k = 0; k < WIN; ++k) {
            float v = RAW[r * SR + j + k];
            s += v * v;
        }
        T[r * ST + j] = s;
    }
    __syncthreads();
    float* dst = out + (long)blockIdx.z * HWSZ;
    for (int e = tid; e < TS * TS; e += 256) {
        int pr = e >> 5, pc = e & 31;
        float s = 0.f;
#pragma unroll
        for (int k = 0; k < WIN; ++k) s += T[(pr + k) * ST + pc];
        dst[(long)(tr0 + pr) * IMG + tc0 + pc] = s;
    }
}

// ---------------------------------------------------------------------------
// Sliding-window helpers for the full-size (32-image) path.

template <int W> struct WinDims {
    static constexpr int A  = (W + 3) & ~3;
    static constexpr int NU = A + W + 8;              // elements actually used
    static constexpr int NF = (NU + 3) / 4;           // 4-elem chunks loaded
    static constexpr int NV = NF * 4;                 // padded array size
};

template <int W>
__device__ __forceinline__ void loadRowWin(const float* __restrict__ row, int c0,
                                           float* v) {
    constexpr int A = WinDims<W>::A;
    constexpr int NF = WinDims<W>::NF;
#pragma unroll
    for (int f = 0; f < NF; ++f) {
        const int cb = c0 - A + 4 * f;
        if (cb >= 0 && cb + 3 < IMG) {
            const float4 t = *(const float4*)(row + cb);
            v[4 * f + 0] = t.x; v[4 * f + 1] = t.y;
            v[4 * f + 2] = t.z; v[4 * f + 3] = t.w;
        } else {
#pragma unroll
            for (int u = 0; u < 4; ++u) {
                const int c = cb + u;
                v[4 * f + u] = (c >= 0 && c < IMG) ? row[c] : 0.f;
            }
        }
    }
}

template <int W>
__device__ __forceinline__ void loadRowWinH(const half_t* __restrict__ row, int c0,
                                            float* v) {
    constexpr int A = WinDims<W>::A;
    constexpr int NF = WinDims<W>::NF;
#pragma unroll
    for (int f = 0; f < NF; ++f) {
        const int cb = c0 - A + 4 * f;   // multiple of 4 -> 8B aligned
        if (cb >= 0 && cb + 3 < IMG) {
            const half4v t = *(const half4v*)(row + cb);
            v[4 * f + 0] = (float)t[0]; v[4 * f + 1] = (float)t[1];
            v[4 * f + 2] = (float)t[2]; v[4 * f + 3] = (float)t[3];
        } else {
#pragma unroll
            for (int u = 0; u < 4; ++u) {
                const int c = cb + u;
                v[4 * f + u] = (c >= 0 && c < IMG) ? (float)row[c] : 0.f;
            }
        }
    }
}

// ---------------------------------------------------------------------------
// XCD-aware decode for the full-size tile kernels (2048-block flat grids).
// HW dispatch round-robins consecutive block ids across the 8 XCDs; decoding
// z from (id&7) gives each XCD 4 whole band-images, so vertical-halo
// neighbor tiles and the per-batch shared fields stay XCD-L2-resident.
__device__ __forceinline__ void xcdDecode(int id, int& z, int& tr0, int& tc0) {
    const int xcd = id & 7, inner = id >> 3;
    z = (xcd << 2) | (inner >> 6);
    const int t = inner & 63;
    tr0 = (t >> 3) * 64;
    tc0 = (t & 7) * 64;
}

// ---------------------------------------------------------------------------
// Fused da kernel (replaces kHbox + kVda): per 64x64 tile, H-box raw rows
// into fp32 LDS (per-thread sliding window), one sync, V-box by register
// sliding down columns + epilogue da = orig - box/n (half out).
// LDS pitch 65: both store and gather patterns are 2-way max (free).
// grid 2048 x 256 (XCD-swizzled).
template <int W>
__global__ __launch_bounds__(256) void kDAtile(const float* __restrict__ in,
                                               long sB, long sC,
                                               half_t* __restrict__ out) {
    constexpr int A = WinDims<W>::A;
    constexpr int NV = WinDims<W>::NV;
    constexpr int NRS = 63 + 2 * W;               // staged t rows
    constexpr int LP = 65;                        // float pitch
    constexpr int NN = 4 * W * W;
    __shared__ float T[NRS * LP];
    int z, tr0, tc0;
    xcdDecode(blockIdx.x, z, tr0, tc0);
    const float* img = in + (long)(z >> 3) * sB + (long)(z & 7) * sC;

    // phase 1: t = H-box(raw), rows tr0-W+1 .. tr0+62+W, cols tc0..tc0+63
    for (int e = threadIdx.x; e < NRS * 8; e += 256) {
        const int i = e >> 3, cg = e & 7;
        const int gr = tr0 - W + 1 + i;
        float* dst = &T[i * LP + cg * 8];
        if (gr < 0 || gr >= IMG) {
#pragma unroll
            for (int j = 0; j < 8; ++j) dst[j] = 0.f;
            continue;
        }
        float v[NV];
        loadRowWin<W>(img + (long)gr * IMG, tc0 + cg * 8, v);
        float s = 0.f;
#pragma unroll
        for (int k = A - W + 1; k <= A + W; ++k) s += v[k];
        dst[0] = s;
#pragma unroll
        for (int j = 1; j < 8; ++j) {
            s += v[A + W + j] - v[A - W + j];
            dst[j] = s;
        }
    }
    __syncthreads();

    // phase 2: V-slide + epilogue
    const int c = threadIdx.x & 63, q = threadIdx.x >> 6;
    const int ro0 = q * 16;
    float s = 0.f;
#pragma unroll
    for (int k = 0; k < 2 * W; ++k) s += T[(ro0 + k) * LP + c];
    const float* oz = img + tc0 + c;
    half_t* dz = out + (long)z * HWSZ + tc0 + c;
#pragma unroll
    for (int j = 0; j < 16; ++j) {
        const int r = tr0 + ro0 + j;
        const float o = oz[(long)r * IMG];
        dz[(long)r * IMG] = (half_t)(o - s * (1.0f / NN));
        if (j < 15) s += T[(ro0 + j + 2 * W) * LP + c] - T[(ro0 + j) * LP + c];
    }
}

// ---------------------------------------------------------------------------
// Fused product + H-box staging (verified round 3/4): per 64x64 tile, H-box
// of (da*dshared, da*da) rows into LDS as packed half2(p1,p2).
template <int W>
__device__ __forceinline__ void stageProducts(const half_t* __restrict__ daz,
                                              const float* __restrict__ dsz,
                                              int tr0, int tc0,
                                              unsigned int* L) {
    constexpr int A = WinDims<W>::A;
    constexpr int NU = WinDims<W>::NU;
    constexpr int NV = WinDims<W>::NV;
    constexpr int NRS = 63 + 2 * W;               // staged product rows
    constexpr int LP = 65;                        // uint pitch (4B units)
    for (int e = threadIdx.x; e < NRS * 8; e += 256) {
        const int i = e >> 3, cg = e & 7;
        const int gr = tr0 - W + 1 + i;
        const int c0 = tc0 + cg * 8;
        unsigned int* dst = L + i * LP + cg * 8;
        if (gr < 0 || gr >= IMG) {
#pragma unroll
            for (int j = 0; j < 8; ++j) dst[j] = 0u;
            continue;
        }
        float va[NV], vs[NV];
        loadRowWinH<W>(daz + (long)gr * IMG, c0, va);
        loadRowWin<W>(dsz + (long)gr * IMG, c0, vs);
        float p1[NV], p2[NV];
#pragma unroll
        for (int k = 0; k < NU; ++k) { p1[k] = va[k] * vs[k]; p2[k] = va[k] * va[k]; }
        float s1 = 0.f, s2 = 0.f;
#pragma unroll
        for (int k = A - W + 1; k <= A + W; ++k) { s1 += p1[k]; s2 += p2[k]; }
#pragma unroll
        for (int j = 0; j < 8; ++j) {
            half2v h;
            h[0] = (half_t)s1; h[1] = (half_t)s2;
            dst[j] = __builtin_bit_cast(unsigned int, h);
            if (j < 7) {
                s1 += p1[A + W + 1 + j] - p1[A - W + 1 + j];
                s2 += p2[A + W + 1 + j] - p2[A - W + 1 + j];
            }
        }
    }
}

// ---------------------------------------------------------------------------
// Fully fused structural kernel, single-barrier schedule: stage BOTH product
// pipelines (separate LDS buffers) -> one sync -> V8(thr in regs) -> V2(Y).
// All ~40 independent global loads/thread issue before any dependent
// consumption (issue-early/consume-late); no mid-kernel full-drain barrier.
// LDS 38 KB -> 4 blocks/CU (16 waves/CU cap). grid 2048 x 256 (XCD-swizzled).
__global__ __launch_bounds__(256, 4) void kFusedXY(
    const half_t* __restrict__ daMS,
    const float* __restrict__ daPAN,
    const float* __restrict__ saa,
    const half_t* __restrict__ daOUT,
    const float* __restrict__ dbPAN,
    const float* __restrict__ sbb,
    double* __restrict__ acc) {
    constexpr int LP = 65;
    constexpr int NRS8 = 63 + 16;                 // 79 (w=8)
    constexpr int NRS2 = 63 + 4;                  // 67 (w=2)
    __shared__ unsigned int L8[NRS8 * LP];
    __shared__ unsigned int L2b[NRS2 * LP];
    __shared__ double red[4];
    int z, tr0, tc0;
    xcdDecode(blockIdx.x, z, tr0, tc0);
    const int b = z >> 3;
    const int c = threadIdx.x & 63, q = threadIdx.x >> 6;
    const int ro0 = q * 16;

    // ---- stage both pipelines, then one barrier -------------------------
    stageProducts<8>(daMS + (long)z * HWSZ, daPAN + (long)b * HWSZ, tr0, tc0, L8);
    stageProducts<2>(daOUT + (long)z * HWSZ, dbPAN + (long)b * HWSZ, tr0, tc0, L2b);
    __syncthreads();

    float thrv[16];
    {   // ---------------- w = 8: thr ----------------
        constexpr int W = 8;
        float s1 = 0.f, s2 = 0.f;
#pragma unroll
        for (int k = 0; k < 2 * W; ++k) {
            const half2v h = __builtin_bit_cast(half2v, L8[(ro0 + k) * LP + c]);
            s1 += (float)h[0]; s2 += (float)h[1];
        }
        const float* sz = saa + (long)b * HWSZ + tc0 + c;
#pragma unroll
        for (int j = 0; j < 16; ++j) {
            const int r = tr0 + ro0 + j;
            const float sa = sz[(long)r * IMG];
            const float den = sqrtf(fmaxf(sa * s2, 0.f)) + 1e-20f;
            thrv[j] = 1.0f - s1 / den;
            if (j < 15) {
                const half2v ha = __builtin_bit_cast(half2v, L8[(ro0 + j + 2 * W) * LP + c]);
                const half2v hs = __builtin_bit_cast(half2v, L8[(ro0 + j) * LP + c]);
                s1 += (float)ha[0] - (float)hs[0];
                s2 += (float)ha[1] - (float)hs[1];
            }
        }
    }
    double ysum = 0.0;
    {   // ---------------- w = 2: X vs thr, Y ---------- (no barrier needed)
        constexpr int W = 2;
        float s1 = 0.f, s2 = 0.f;
#pragma unroll
        for (int k = 0; k < 2 * W; ++k) {
            const half2v h = __builtin_bit_cast(half2v, L2b[(ro0 + k) * LP + c]);
            s1 += (float)h[0]; s2 += (float)h[1];
        }
        const float* sz = sbb + (long)b * HWSZ + tc0 + c;
#pragma unroll
        for (int j = 0; j < 16; ++j) {
            const float sb = sz[(long)(tr0 + ro0 + j) * IMG];
            const float den = sqrtf(fmaxf(s2 * sb, 0.f)) + 1e-20f;
            const float Xc = s1 / den;
            const float X = 1.0f - fmaxf(Xc, -1.0f);
            if (X > thrv[j]) ysum += (double)X;
            if (j < 15) {
                const half2v ha = __builtin_bit_cast(half2v, L2b[(ro0 + j + 2 * W) * LP + c]);
                const half2v hs = __builtin_bit_cast(half2v, L2b[(ro0 + j) * LP + c]);
                s1 += (float)ha[0] - (float)hs[0];
                s2 += (float)ha[1] - (float)hs[1];
            }
        }
    }
    blockReduceAtomicAdd(ysum, acc + 2, red);
}

// ---------------------------------------------------------------------------
// L_spec: strided MTF conv of outputs (rank-1 factored), H then V+reduce.
__global__ __launch_bounds__(256) void k_spec_h(const float* __restrict__ outputs,
                                                const float* __restrict__ mtf,
                                                float* __restrict__ tmpS) {
    __shared__ float vrow[41];
    const int g = blockIdx.x * 256 + threadIdx.x;
    const int q = g & 31, r = (g >> 5) & 511, z = g >> 14;   // z uniform/block
    const int band = z & 7;
    if (threadIdx.x < 41)
        vrow[threadIdx.x] = mtf[band * 1681 + 20 * 41 + threadIdx.x] /
                            sqrtf(mtf[band * 1681 + 20 * 41 + 20]);
    __syncthreads();
    const float* row = outputs + (long)z * HWSZ + (long)r * IMG;
    float v[56];
#pragma unroll
    for (int f = 0; f < 14; ++f) {
        const int cb = 16 * q - 20 + 4 * f;
        if (cb >= 0 && cb + 3 < IMG) {
            const float4 t = *(const float4*)(row + cb);
            v[4 * f + 0] = t.x; v[4 * f + 1] = t.y;
            v[4 * f + 2] = t.z; v[4 * f + 3] = t.w;
        } else {
#pragma unroll
            for (int u = 0; u < 4; ++u) {
                const int cc = cb + u;
                v[4 * f + u] = (cc >= 0 && cc < IMG) ? row[cc] : 0.f;
            }
        }
    }
    float o[4] = {0.f, 0.f, 0.f, 0.f};
#pragma unroll
    for (int j = 0; j < 41; ++j) {
        const float w = vrow[j];
#pragma unroll
        for (int u = 0; u < 4; ++u) o[u] += w * v[2 + 4 * u + j];
    }
    float* dst = tmpS + ((long)z * IMG + r) * 128 + 4 * q;
    *(float4*)dst = make_float4(o[0], o[1], o[2], o[3]);
}

__global__ __launch_bounds__(256) void k_spec_v(const float* __restrict__ tmpS,
                                                const float* __restrict__ labels,
                                                const float* __restrict__ spec,
                                                const float* __restrict__ mtf,
                                                double* __restrict__ acc) {
    __shared__ double redT[4];
    __shared__ double redM[4];
    __shared__ float ucol[41];
    const int g = blockIdx.x * 256 + threadIdx.x;
    const int q = g & 31, rs = (g >> 5) & 127, z = g >> 12;   // z uniform/block
    const int b = z >> 3, band = z & 7;
    if (threadIdx.x < 41)
        ucol[threadIdx.x] = mtf[band * 1681 + threadIdx.x * 41 + 20] /
                            sqrtf(mtf[band * 1681 + 20 * 41 + 20]);
    __syncthreads();
    const float* base = tmpS + (long)z * IMG * 128 + 4 * q;
    const int rbase = 4 * rs - 18;
    float o[4] = {0.f, 0.f, 0.f, 0.f};
    if (rbase >= 0 && rbase + 40 < IMG) {
#pragma unroll
        for (int i = 0; i < 41; ++i) {
            const float4 v = *(const float4*)(base + (long)(rbase + i) * 128);
            const float w = ucol[i];
            o[0] += w * v.x; o[1] += w * v.y; o[2] += w * v.z; o[3] += w * v.w;
        }
    } else {
        for (int i = 0; i < 41; ++i) {
            const int r = rbase + i;
            if (r >= 0 && r < IMG) {
                const float4 v = *(const float4*)(base + (long)r * 128);
                const float w = ucol[i];
                o[0] += w * v.x; o[1] += w * v.y; o[2] += w * v.z; o[3] += w * v.w;
            }
        }
    }
    const int gr = 2 + 4 * rs;
    float tsum = 0.f, msum = 0.f;
#pragma unroll
    for (int u = 0; u < 4; ++u) {
        const int gc = 2 + 4 * (4 * q + u);
        const float m = spec[(long)band * HWSZ + (long)gr * IMG + gc];
        const float y = labels[((long)b * 9 + band) * HWSZ + (long)gr * IMG + gc];
        tsum += fabsf(o[u] * m - y * m);
        msum += m;
    }
    blockReduceAtomicAdd((double)tsum, acc + 0, redT);
    blockReduceAtomicAdd((double)msum, acc + 1, redM);
}

__global__ void k_final(const double* __restrict__ acc, float* __restrict__ out) {
    double lspec = acc[0] / acc[1];
    double lstruct = acc[2] / (double)(NBATCH * NBANDS * HWSZ);
    out[0] = (float)(lspec + 0.25 * lstruct);
}

// ---------------------------------------------------------------------------
extern "C" void kernel_launch(void* const* d_in, const int* in_sizes, int n_in,
                              void* d_out, int out_size, void* d_ws, size_t ws_size,
                              hipStream_t stream) {
    const float* outputs = (const float*)d_in[0];   // (4,8,512,512)
    const float* labels  = (const float*)d_in[1];   // (4,9,512,512)
    const float* inp     = (const float*)d_in[2];   // (4,9,512,512)
    const float* mtf     = (const float*)d_in[3];   // (8,1,41,41)
    const float* spec    = (const float*)d_in[4];   // (1,8,512,512)
    float* out = (float*)d_out;

    const long IMGB = (long)HWSZ;     // one image in elements
    char* ws = (char*)d_ws;
    double* acc    = (double*)ws;                    // 4 doubles
    float* panf    = (float*)(ws + 1024);            // 4 imgs fp32
    float* tmpH    = panf   + NBATCH * IMGB;         // 4 imgs
    float* da_pan8 = tmpH   + NBATCH * IMGB;         // 4 imgs
    float* saa8    = da_pan8 + NBATCH * IMGB;        // 4 imgs
    float* db_pan2 = saa8   + NBATCH * IMGB;         // 4 imgs
    float* sbb2    = db_pan2 + NBATCH * IMGB;        // 4 imgs
    float* tmpS    = sbb2   + NBATCH * IMGB;         // 8 imgs fp32
    half_t* hDA8   = (half_t*)(tmpS + 8 * IMGB);     // 32 imgs half: da_ms  (w=8)
    half_t* hDA2   = hDA8 + 32 * IMGB;               // 32 imgs half: da_out (w=2)

    hipMemsetAsync(acc, 0, 4 * sizeof(double), stream);

    // --- per-batch shared fields (fp32) ----------------------------------
    k_pan_h<<<dim3(2, 512, NBATCH), 256, 0, stream>>>(inp, mtf, tmpH);
    k_pan_v<<<dim3(2, 512, NBATCH), 256, 0, stream>>>(tmpH, mtf, panf);
    k_da<8><<<dim3(16, 16, NBATCH), 256, 0, stream>>>(panf, (long)HWSZ, da_pan8);
    k_sq<8><<<dim3(16, 16, NBATCH), 256, 0, stream>>>(da_pan8, saa8);
    k_da<2><<<dim3(16, 16, NBATCH), 256, 0, stream>>>(labels + 8 * IMGB,
                                                      (long)9 * HWSZ, db_pan2);
    k_sq<2><<<dim3(16, 16, NBATCH), 256, 0, stream>>>(db_pan2, sbb2);

    // --- L_spec ----------------------------------------------------------
    k_spec_h<<<2048, 256, 0, stream>>>(outputs, mtf, tmpS);
    k_spec_v<<<512, 256, 0, stream>>>(tmpS, labels, spec, mtf, acc);

    // --- da fields for both xcorr widths (fused H+V box, XCD-swizzled) ---
    kDAtile<8><<<2048, 256, 0, stream>>>(inp, 9 * IMGB, IMGB, hDA8);
    kDAtile<2><<<2048, 256, 0, stream>>>(outputs, 8 * IMGB, IMGB, hDA2);

    // --- fused products + box + thr + X + Y reduce (single barrier) -------
    kFusedXY<<<2048, 256, 0, stream>>>(hDA8, da_pan8, saa8,
                                       hDA2, db_pan2, sbb2, acc);

    k_final<<<1, 1, 0, stream>>>(acc, out);
}